// Round 4
// baseline (6089.954 us; speedup 1.0000x reference)
//
#include <hip/hip_runtime.h>
#include <stdint.h>

// Problem constants
#define NB      16
#define NPTS    4096
#define CPTS    64
#define NPOINT  1024
#define NSAMPLE 32
#define NROWS   (NB*NPOINT*NSAMPLE)   // 524288 rows of (b,s,k)

// f32 -> bf16 (RNE) and bf16 -> f32 (intermediates only; in/out are f32)
__device__ __forceinline__ unsigned short f2bf(float f){
  uint32_t u = __float_as_uint(f);
  uint32_t r = u + 0x7fffu + ((u>>16)&1u);
  return (unsigned short)(r>>16);
}
__device__ __forceinline__ float bf2f(unsigned short u){ return __uint_as_float(((uint32_t)u)<<16); }
__device__ __forceinline__ float lo16(uint32_t d){ return __uint_as_float(d<<16); }
__device__ __forceinline__ float hi16(uint32_t d){ return __uint_as_float(d & 0xffff0000u); }
__device__ __forceinline__ uint32_t pack2(float a, float b){ return ((uint32_t)f2bf(b)<<16) | (uint32_t)f2bf(a); }

// ---------------------------------------------------------------------------
// K1: Farthest point sampling. 1 block/batch, 512 threads, 8 pts/thread in
// registers. Exact f32 arithmetic (no FMA contraction) matching numpy order
// ((dx*dx+dy*dy)+dz*dz); strict-> argmax => first-occurrence tie-break.
// One barrier per iteration via double-buffered per-wave reduction slots.
// ---------------------------------------------------------------------------
__global__ __launch_bounds__(512) void fps_kernel(const float* __restrict__ xyz,
                                                  float* __restrict__ newxyz_f,
                                                  float* __restrict__ out){
  __shared__ float s_x[NPTS], s_y[NPTS], s_z[NPTS];
  __shared__ float s_rv[2][8];
  __shared__ int   s_ri[2][8];
  const int b = blockIdx.x, t = threadIdx.x;
  const float* Xb = xyz + (size_t)b*NPTS*3;
  float px[8], py[8], pz[8], dd[8];
  #pragma unroll
  for (int i=0;i<8;++i){
    int n = t*8+i;
    float x = Xb[n*3+0], y = Xb[n*3+1], z = Xb[n*3+2];
    px[i]=x; py[i]=y; pz[i]=z; dd[i]=1e10f;
    s_x[n]=x; s_y[n]=y; s_z[n]=z;
  }
  if (t==0){
    size_t o=(size_t)b*NPOINT*3;   // sample 0 is index 0 (scan emits prior carry)
    newxyz_f[o]=px[0]; newxyz_f[o+1]=py[0]; newxyz_f[o+2]=pz[0];
    out[o]=px[0]; out[o+1]=py[0]; out[o+2]=pz[0];
  }
  __syncthreads();
  float cx=s_x[0], cy=s_y[0], cz=s_z[0];
  const int lane = t&63, wid = t>>6;
  for (int s=1;s<NPOINT;++s){
    float bv=-1.0f; int bi=0;
    #pragma unroll
    for (int i=0;i<8;++i){
      float dx=__fsub_rn(px[i],cx), dy=__fsub_rn(py[i],cy), dz=__fsub_rn(pz[i],cz);
      float d=__fadd_rn(__fadd_rn(__fmul_rn(dx,dx),__fmul_rn(dy,dy)),__fmul_rn(dz,dz));
      float nd=fminf(dd[i],d); dd[i]=nd;
      if (nd>bv){ bv=nd; bi=t*8+i; }    // ascending i + strict > => lowest idx on tie
    }
    #pragma unroll
    for (int off=32; off>0; off>>=1){
      float ov=__shfl_down(bv,off,64);
      int   oi=__shfl_down(bi,off,64);
      if (ov>bv || (ov==bv && oi<bi)){ bv=ov; bi=oi; }
    }
    const int buf = s&1;
    if (lane==0){ s_rv[buf][wid]=bv; s_ri[buf][wid]=bi; }
    __syncthreads();
    float fv=s_rv[buf][0]; int fi=s_ri[buf][0];
    #pragma unroll
    for (int w=1;w<8;++w){
      float ov=s_rv[buf][w]; int oi=s_ri[buf][w];
      if (ov>fv || (ov==fv && oi<fi)){ fv=ov; fi=oi; }
    }
    cx=s_x[fi]; cy=s_y[fi]; cz=s_z[fi];
    if (t==0){
      size_t o=((size_t)b*NPOINT+s)*3;
      newxyz_f[o]=cx; newxyz_f[o+1]=cy; newxyz_f[o+2]=cz;
      out[o]=cx; out[o+1]=cy; out[o+2]=cz;
    }
    // no 2nd barrier: next iter writes the OTHER s_rv buffer; reaching that
    // write requires passing this barrier, which all waves' reads precede.
  }
}

// ---------------------------------------------------------------------------
// K2: Ball query. One wave per center; batch xyz staged in LDS. First NSAMPLE
// in-radius indices in ascending j (== sort semantics) via ballot + prefix
// popcount; pad with first index.
// ---------------------------------------------------------------------------
__global__ __launch_bounds__(256) void ballq_kernel(const float* __restrict__ xyz,
                                                    const float* __restrict__ newxyz_f,
                                                    int* __restrict__ ballidx){
  __shared__ float s_x[NPTS], s_y[NPTS], s_z[NPTS];
  __shared__ int s_list[4][NSAMPLE];
  const int b  = blockIdx.x >> 8;     // 256 s-groups per batch
  const int sg = blockIdx.x & 255;
  const int t = threadIdx.x;
  const float* Xb = xyz + (size_t)b*NPTS*3;
  for (int n=t;n<NPTS;n+=256){
    s_x[n]=Xb[n*3+0]; s_y[n]=Xb[n*3+1]; s_z[n]=Xb[n*3+2];
  }
  __syncthreads();
  const int lane = t&63, wid = t>>6;
  const int s = sg*4 + wid;
  size_t co = ((size_t)b*NPOINT+s)*3;
  const float cx=newxyz_f[co], cy=newxyz_f[co+1], cz=newxyz_f[co+2];
  const float R2 = 0.04f;             // f32(0.2**2), NEP-50 weak-scalar promotion
  int count = 0;
  for (int j0=0; j0<NPTS && count<NSAMPLE; j0+=64){
    int j=j0+lane;
    float dx=__fsub_rn(cx,s_x[j]), dy=__fsub_rn(cy,s_y[j]), dz=__fsub_rn(cz,s_z[j]);
    float sq=__fadd_rn(__fadd_rn(__fmul_rn(dx,dx),__fmul_rn(dy,dy)),__fmul_rn(dz,dz));
    bool in = !(sq > R2);
    unsigned long long m = __ballot(in);
    int before = __popcll(m & ((1ull<<lane)-1ull));
    int pos = count + before;
    if (in && pos < NSAMPLE) s_list[wid][pos] = j;
    count += __popcll(m);
  }
  int c = count < NSAMPLE ? count : NSAMPLE;   // >=1: center is in its own ball
  int first = s_list[wid][0];
  if (lane >= c && lane < NSAMPLE) s_list[wid][lane] = first;
  if (lane < NSAMPLE) ballidx[((size_t)b*NPOINT+s)*NSAMPLE + lane] = s_list[wid][lane];
}

// ---------------------------------------------------------------------------
// K3: layer 1 — gather + concat + (67 -> 64) matmul + bias -> h (bf16).
// Two 32-channel passes (acc[32]) to keep VGPR <= 128 (anti-spill: R3 showed
// acc[64] variants spill to scratch -> GBs of phantom HBM traffic).
// ---------------------------------------------------------------------------
__global__ __launch_bounds__(256,4) void layer1_kernel(const float* __restrict__ xyz,
    const float* __restrict__ points, const int* __restrict__ ballidx,
    const float* __restrict__ newxyz_f, const float* __restrict__ w0,
    const float* __restrict__ b0, unsigned short* __restrict__ h){
  __shared__ float s_w[67*64];
  __shared__ float s_b[64];
  const int t = threadIdx.x;
  for (int i=t;i<67*64;i+=256){ int c=i>>6, o=i&63; s_w[i]=w0[o*67+c]; }
  if (t<64) s_b[t]=b0[t];
  __syncthreads();
  const int row = blockIdx.x*256+t;
  const int bs  = row >> 5;           // b*1024+s
  const int bb  = bs >> 10;
  const int j   = ballidx[row];
  const float* cp = newxyz_f + (size_t)bs*3;
  const float* xr = xyz + ((size_t)bb*NPTS + (size_t)j)*3;
  float in3[3];
  in3[0] = (xr[0]-cp[0])/0.2f;
  in3[1] = (xr[1]-cp[1])/0.2f;
  in3[2] = (xr[2]-cp[2])/0.2f;
  const float* pr = points + ((size_t)bb*NPTS + (size_t)j)*CPTS;
  const float4* pr4=(const float4*)pr;
  #pragma unroll 1
  for (int pass=0; pass<2; ++pass){
    const int po = pass*32;
    float acc[32];
    #pragma unroll
    for (int o=0;o<32;++o) acc[o]=0.0f;
    #pragma unroll
    for (int c=0;c<3;++c){
      float xv=in3[c];
      const float4* wr=(const float4*)(s_w + c*64 + po);
      #pragma unroll
      for (int q=0;q<8;++q){ float4 w=wr[q];
        acc[4*q+0]=fmaf(xv,w.x,acc[4*q+0]); acc[4*q+1]=fmaf(xv,w.y,acc[4*q+1]);
        acc[4*q+2]=fmaf(xv,w.z,acc[4*q+2]); acc[4*q+3]=fmaf(xv,w.w,acc[4*q+3]); }
    }
    #pragma unroll
    for (int cc=0;cc<16;++cc){
      float4 pv=pr4[cc];   // L1-hot on pass 1
      float xs[4]={pv.x,pv.y,pv.z,pv.w};
      #pragma unroll
      for (int jj=0;jj<4;++jj){
        int c=3+cc*4+jj;
        float xv=xs[jj];
        const float4* wr=(const float4*)(s_w + c*64 + po);
        #pragma unroll
        for (int q=0;q<8;++q){ float4 w=wr[q];
          acc[4*q+0]=fmaf(xv,w.x,acc[4*q+0]); acc[4*q+1]=fmaf(xv,w.y,acc[4*q+1]);
          acc[4*q+2]=fmaf(xv,w.z,acc[4*q+2]); acc[4*q+3]=fmaf(xv,w.w,acc[4*q+3]); }
      }
    }
    uint4* od=(uint4*)(h + (size_t)row*64 + po);
    #pragma unroll
    for (int q=0;q<4;++q){
      uint4 v;
      v.x=pack2(acc[8*q+0]+s_b[po+8*q+0], acc[8*q+1]+s_b[po+8*q+1]);
      v.y=pack2(acc[8*q+2]+s_b[po+8*q+2], acc[8*q+3]+s_b[po+8*q+3]);
      v.z=pack2(acc[8*q+4]+s_b[po+8*q+4], acc[8*q+5]+s_b[po+8*q+5]);
      v.w=pack2(acc[8*q+6]+s_b[po+8*q+6], acc[8*q+7]+s_b[po+8*q+7]);
      od[q]=v;
    }
  }
}

// ---------------------------------------------------------------------------
// Stats over h (bf16, C=64): per-channel sum/sumsq. Wave reads 8 rows/iter as
// uint4 (1KB/wave-inst, fully coalesced); each lane owns 8 fixed channels.
// LDS block-reduce, then one atomicAdd pair per channel per block.
// ---------------------------------------------------------------------------
__global__ __launch_bounds__(256) void stats64_kernel(const unsigned short* __restrict__ h,
                                                      float* __restrict__ st){
  __shared__ float s_red[4][64][8], s_red2[4][64][8];
  const int t=threadIdx.x, lane=t&63, wid=t>>6;
  const int gw = blockIdx.x*4+wid;         // 512 blocks -> 0..2047 waves
  const int rsub = lane>>3;
  float sm[8], sq[8];
  #pragma unroll
  for (int j=0;j<8;++j){ sm[j]=0.f; sq[j]=0.f; }
  for (int it=0; it<32; ++it){
    size_t row = (size_t)gw*256 + it*8 + rsub;
    const uint4* p = (const uint4*)(h + row*64) + (lane&7);
    uint4 v = *p;
    uint32_t ds4[4]={v.x,v.y,v.z,v.w};
    #pragma unroll
    for (int dj=0;dj<4;++dj){
      float a=lo16(ds4[dj]), b2=hi16(ds4[dj]);
      sm[2*dj]+=a;   sq[2*dj]  =fmaf(a,a,sq[2*dj]);
      sm[2*dj+1]+=b2; sq[2*dj+1]=fmaf(b2,b2,sq[2*dj+1]);
    }
  }
  #pragma unroll
  for (int j=0;j<8;++j){ s_red[wid][lane][j]=sm[j]; s_red2[wid][lane][j]=sq[j]; }
  __syncthreads();
  if (t<64){
    // channel t: lanes l with (l&7)==t>>3, element t&7
    float ts=0.f,tq=0.f;
    #pragma unroll
    for (int w=0;w<4;++w)
      #pragma unroll
      for (int m=0;m<8;++m){ int l=(t>>3)+8*m; ts+=s_red[w][l][t&7]; tq+=s_red2[w][l][t&7]; }
    atomicAdd(&st[t*2], ts); atomicAdd(&st[t*2+1], tq);
  }
}

// ---------------------------------------------------------------------------
// K4: layer 2 — BN(stats0)+ReLU on the fly, (64 -> 64) matmul + bias, written
// IN PLACE over the same row. Row kept packed in 32 regs across both
// 32-channel passes (anti-spill split).
// ---------------------------------------------------------------------------
__global__ __launch_bounds__(256,3) void layer2_kernel(unsigned short* __restrict__ h,
    const float* __restrict__ st, const float* __restrict__ g,
    const float* __restrict__ be, const float* __restrict__ w1,
    const float* __restrict__ b1){
  __shared__ float s_w[64*64];
  __shared__ float s_b[64], s_scale[64], s_shift[64];
  const int t=threadIdx.x;
  for (int i=t;i<64*64;i+=256){ int c=i>>6, o=i&63; s_w[i]=w1[o*64+c]; }
  if (t<64){
    s_b[t]=b1[t];
    float mu=st[t*2]*(1.0f/NROWS);
    float var=st[t*2+1]*(1.0f/NROWS)-mu*mu;
    float inv=1.0f/sqrtf(var+1e-5f);
    s_scale[t]=inv*g[t]; s_shift[t]=be[t]-mu*inv*g[t];
  }
  __syncthreads();
  const size_t row = (size_t)blockIdx.x*256+t;
  unsigned short* hr = h + row*64;
  uint32_t rowd[32];
  const uint4* hv=(const uint4*)hr;
  #pragma unroll
  for (int cc=0;cc<8;++cc){ uint4 rv=hv[cc];
    rowd[4*cc]=rv.x; rowd[4*cc+1]=rv.y; rowd[4*cc+2]=rv.z; rowd[4*cc+3]=rv.w; }
  #pragma unroll 1
  for (int pass=0; pass<2; ++pass){
    const int po = pass*32;
    float acc[32];
    #pragma unroll
    for (int o=0;o<32;++o) acc[o]=0.0f;
    #pragma unroll
    for (int c=0;c<64;++c){
      uint32_t d=rowd[c>>1];
      float x=(c&1)? hi16(d):lo16(d);
      x=fmaxf(fmaf(x,s_scale[c],s_shift[c]),0.0f);
      const float4* wr=(const float4*)(s_w + c*64 + po);
      #pragma unroll
      for (int q=0;q<8;++q){ float4 w=wr[q];
        acc[4*q+0]=fmaf(x,w.x,acc[4*q+0]); acc[4*q+1]=fmaf(x,w.y,acc[4*q+1]);
        acc[4*q+2]=fmaf(x,w.z,acc[4*q+2]); acc[4*q+3]=fmaf(x,w.w,acc[4*q+3]); }
    }
    uint4* od=(uint4*)(hr + po);
    #pragma unroll
    for (int q=0;q<4;++q){
      uint4 v;
      v.x=pack2(acc[8*q+0]+s_b[po+8*q+0], acc[8*q+1]+s_b[po+8*q+1]);
      v.y=pack2(acc[8*q+2]+s_b[po+8*q+2], acc[8*q+3]+s_b[po+8*q+3]);
      v.z=pack2(acc[8*q+4]+s_b[po+8*q+4], acc[8*q+5]+s_b[po+8*q+5]);
      v.w=pack2(acc[8*q+6]+s_b[po+8*q+6], acc[8*q+7]+s_b[po+8*q+7]);
      od[q]=v;
    }
  }
}

// ---------------------------------------------------------------------------
// K5: layer 3 fused — BN(stats1)+ReLU, (64 -> 128) matmul + bias, per-s
// max/min over K=32 (h3 never materialized) + BN3 stats accumulation.
// Block 256 = 4 waves; wave owns 8 s-groups; lane = (k, half-of-channels).
// Channel work split into two 32-wide passes (acc[32]) — R3's acc[64] version
// spilled (VGPR=256, 1.2 GB phantom FETCH). Row packed in rowd[32] regs.
// Per-wave LDS tile [32][136] bf16 transposes k->columns for the reduction.
// ---------------------------------------------------------------------------
__global__ __launch_bounds__(256,3) void layer3mm_kernel(const unsigned short* __restrict__ h,
    const float* __restrict__ st, const float* __restrict__ g,
    const float* __restrict__ be, const float* __restrict__ w2,
    const float* __restrict__ b2, float* __restrict__ mm, float* __restrict__ st2){
  __shared__ unsigned short s_w[64*128];        // 16KB  s_w[c*128+o]=bf16(w2[o][c])
  __shared__ unsigned short s_tile[4][32*136];  // 34816B, +8 u16 row pad
  __shared__ float s_scale[64], s_shift[64], s_b2[128];
  __shared__ float s_sum[4][128], s_sq[4][128]; // 4KB
  const int t=threadIdx.x, lane=t&63, wid=t>>6;
  for (int i=t;i<64*128;i+=256){ int c=i>>7, o=i&127; s_w[i]=f2bf(w2[o*64+c]); }
  if (t<64){
    float mu=st[t*2]*(1.0f/NROWS);
    float var=st[t*2+1]*(1.0f/NROWS)-mu*mu;
    float inv=1.0f/sqrtf(var+1e-5f);
    s_scale[t]=inv*g[t]; s_shift[t]=be[t]-mu*inv*g[t];
  }
  if (t<128) s_b2[t]=b2[t];
  __syncthreads();
  const int k=lane&31, half=lane>>5, oo=half*64;
  unsigned short* tile = s_tile[wid];
  const int waveG = blockIdx.x*4+wid;           // 512 blocks -> 0..2047
  float sumA=0.f,sqA=0.f,sumB=0.f,sqB=0.f;
  for (int i2=0;i2<8;++i2){
    const int s = waveG*8 + i2;
    const unsigned short* hp = h + ((size_t)s*32 + (size_t)k)*64;
    uint32_t rowd[32];
    const uint4* hv=(const uint4*)hp;
    #pragma unroll
    for (int cc=0;cc<8;++cc){ uint4 rv=hv[cc];
      rowd[4*cc]=rv.x; rowd[4*cc+1]=rv.y; rowd[4*cc+2]=rv.z; rowd[4*cc+3]=rv.w; }
    #pragma unroll 1
    for (int pass=0; pass<2; ++pass){
      const int po = pass*32;
      float acc[32];
      #pragma unroll
      for (int o=0;o<32;++o) acc[o]=0.0f;
      #pragma unroll
      for (int c=0;c<64;++c){
        uint32_t d=rowd[c>>1];
        float x=(c&1)? hi16(d):lo16(d);
        x=fmaxf(fmaf(x,s_scale[c],s_shift[c]),0.0f);
        const uint4* wr=(const uint4*)(s_w + (size_t)c*128 + oo + po);
        #pragma unroll
        for (int q=0;q<4;++q){
          uint4 wu=wr[q];
          acc[8*q+0]=fmaf(x,lo16(wu.x),acc[8*q+0]); acc[8*q+1]=fmaf(x,hi16(wu.x),acc[8*q+1]);
          acc[8*q+2]=fmaf(x,lo16(wu.y),acc[8*q+2]); acc[8*q+3]=fmaf(x,hi16(wu.y),acc[8*q+3]);
          acc[8*q+4]=fmaf(x,lo16(wu.z),acc[8*q+4]); acc[8*q+5]=fmaf(x,hi16(wu.z),acc[8*q+5]);
          acc[8*q+6]=fmaf(x,lo16(wu.w),acc[8*q+6]); acc[8*q+7]=fmaf(x,hi16(wu.w),acc[8*q+7]);
        }
      }
      // + bias, pack to wave tile row k, channels [oo+po, oo+po+32)
      uint4* tw=(uint4*)(tile + (size_t)k*136 + oo + po);
      #pragma unroll
      for (int q=0;q<4;++q){
        uint4 v;
        v.x=pack2(acc[8*q+0]+s_b2[oo+po+8*q+0], acc[8*q+1]+s_b2[oo+po+8*q+1]);
        v.y=pack2(acc[8*q+2]+s_b2[oo+po+8*q+2], acc[8*q+3]+s_b2[oo+po+8*q+3]);
        v.z=pack2(acc[8*q+4]+s_b2[oo+po+8*q+4], acc[8*q+5]+s_b2[oo+po+8*q+5]);
        v.w=pack2(acc[8*q+6]+s_b2[oo+po+8*q+6], acc[8*q+7]+s_b2[oo+po+8*q+7]);
        tw[q]=v;
      }
    }
    // wave-coherent LDS (in-order DS pipe, lockstep wave64): no barrier.
    // Column reduce: lane owns channels (lane, lane+64) over k=0..31.
    float mxA=-3e38f, mnA=3e38f, mxB=-3e38f, mnB=3e38f;
    float sA=0.f,qA=0.f,sB=0.f,qB=0.f;
    #pragma unroll
    for (int kk=0;kk<32;++kk){
      float a = bf2f(tile[kk*136 + lane]);
      float b3= bf2f(tile[kk*136 + lane + 64]);
      mxA=fmaxf(mxA,a); mnA=fminf(mnA,a); sA+=a; qA=fmaf(a,a,qA);
      mxB=fmaxf(mxB,b3); mnB=fminf(mnB,b3); sB+=b3; qB=fmaf(b3,b3,qB);
    }
    float* mp = mm + (size_t)s*256;
    mp[lane]      = mxA; mp[lane+64]  = mxB;    // max plane
    mp[128+lane]  = mnA; mp[192+lane] = mnB;    // min plane
    sumA+=sA; sqA+=qA; sumB+=sB; sqB+=qB;
  }
  s_sum[wid][lane]=sumA; s_sum[wid][lane+64]=sumB;
  s_sq [wid][lane]=sqA;  s_sq [wid][lane+64]=sqB;
  __syncthreads();
  if (t<128){
    float ts=0.f,tq=0.f;
    #pragma unroll
    for (int w=0;w<4;++w){ ts+=s_sum[w][t]; tq+=s_sq[w][t]; }
    atomicAdd(&st2[t*2], ts); atomicAdd(&st2[t*2+1], tq);
  }
}

// ---------------------------------------------------------------------------
// K6: BN(stats2) on max (or min if scale<0) + ReLU -> new_points (f32).
// ---------------------------------------------------------------------------
__global__ __launch_bounds__(256) void final_kernel(const float* __restrict__ mm,
    const float* __restrict__ st, const float* __restrict__ g,
    const float* __restrict__ be, float* __restrict__ out){
  __shared__ float s_scale[128], s_shift[128];
  const int t=threadIdx.x;
  if (t<128){
    float mu=st[t*2]*(1.0f/NROWS);
    float var=st[t*2+1]*(1.0f/NROWS)-mu*mu;
    float inv=1.0f/sqrtf(var+1e-5f);
    s_scale[t]=inv*g[t]; s_shift[t]=be[t]-mu*inv*g[t];
  }
  __syncthreads();
  const int idx = blockIdx.x*256+t;       // bs*128 + ch
  const int ch = idx & 127, bs = idx >> 7;
  float sc=s_scale[ch];
  float v = (sc>=0.f)? mm[(size_t)bs*256+ch] : mm[(size_t)bs*256+128+ch];
  out[(size_t)NB*NPOINT*3 + idx] = fmaxf(fmaf(v,sc,s_shift[ch]),0.0f);
}

// ---------------------------------------------------------------------------
extern "C" void kernel_launch(void* const* d_in, const int* in_sizes, int n_in,
                              void* d_out, int out_size, void* d_ws, size_t ws_size,
                              hipStream_t stream) {
  const float* xyz    = (const float*)d_in[0];
  const float* points = (const float*)d_in[1];
  const float* w0 = (const float*)d_in[2];
  const float* b0 = (const float*)d_in[3];
  const float* g0 = (const float*)d_in[4];
  const float* be0= (const float*)d_in[5];
  const float* w1 = (const float*)d_in[6];
  const float* b1 = (const float*)d_in[7];
  const float* g1 = (const float*)d_in[8];
  const float* be1= (const float*)d_in[9];
  const float* w2 = (const float*)d_in[10];
  const float* b2 = (const float*)d_in[11];
  const float* g2 = (const float*)d_in[12];
  const float* be2= (const float*)d_in[13];
  float* out = (float*)d_out;             // f32 output per reference dtype
  char* ws = (char*)d_ws;

  // ws layout (84 MiB total):
  //   [0,        196608)    newxyz_f (16,1024,3) f32
  //   [196608,   2293760)   ballidx  (16,1024,32) i32
  //   [2293760,  2296832)   stats: 3 slots x 256 f32 {sum,sumsq interleaved}
  //   [4 MiB,    20 MiB)    mm: (16384, {max,min}, 128) f32
  //   [20 MiB,   84 MiB)    h: (524288, 64) bf16 — h1, then h2 in place
  float* newxyz_f = (float*)(ws);
  int*   ballidx  = (int*)(ws + 196608);
  float* stats    = (float*)(ws + 2293760);
  float* mm       = (float*)(ws + 4194304);
  unsigned short* h = (unsigned short*)(ws + 20971520);

  hipMemsetAsync(stats, 0, 3072, stream);
  hipLaunchKernelGGL(fps_kernel,     dim3(NB),   dim3(512), 0, stream, xyz, newxyz_f, out);
  hipLaunchKernelGGL(ballq_kernel,   dim3(4096), dim3(256), 0, stream, xyz, newxyz_f, ballidx);
  hipLaunchKernelGGL(layer1_kernel,  dim3(2048), dim3(256), 0, stream,
                     xyz, points, ballidx, newxyz_f, w0, b0, h);
  hipLaunchKernelGGL(stats64_kernel, dim3(512),  dim3(256), 0, stream, h, stats + 0);
  hipLaunchKernelGGL(layer2_kernel,  dim3(2048), dim3(256), 0, stream,
                     h, stats + 0, g0, be0, w1, b1);
  hipLaunchKernelGGL(stats64_kernel, dim3(512),  dim3(256), 0, stream, h, stats + 256);
  hipLaunchKernelGGL(layer3mm_kernel,dim3(512),  dim3(256), 0, stream,
                     h, stats + 256, g1, be1, w2, b2, mm, stats + 512);
  hipLaunchKernelGGL(final_kernel,   dim3(8192), dim3(256), 0, stream,
                     mm, stats + 512, g2, be2, out);
}

// Round 5
// 3989.373 us; speedup vs baseline: 1.5265x; 1.5265x over previous
//
#include <hip/hip_runtime.h>
#include <stdint.h>

// Problem constants
#define NB      16
#define NPTS    4096
#define CPTS    64
#define NPOINT  1024
#define NSAMPLE 32
#define NROWS   (NB*NPOINT*NSAMPLE)   // 524288 rows of (b,s,k)

// f32 -> bf16 (RNE) and bf16 -> f32 (intermediates only; in/out are f32)
__device__ __forceinline__ unsigned short f2bf(float f){
  uint32_t u = __float_as_uint(f);
  uint32_t r = u + 0x7fffu + ((u>>16)&1u);
  return (unsigned short)(r>>16);
}
__device__ __forceinline__ float bf2f(unsigned short u){ return __uint_as_float(((uint32_t)u)<<16); }
__device__ __forceinline__ float lo16(uint32_t d){ return __uint_as_float(d<<16); }
__device__ __forceinline__ float hi16(uint32_t d){ return __uint_as_float(d & 0xffff0000u); }
__device__ __forceinline__ uint32_t pack2(float a, float b){ return ((uint32_t)f2bf(b)<<16) | (uint32_t)f2bf(a); }

// ---------------------------------------------------------------------------
// K1: Farthest point sampling. 1 block/batch, 512 threads, 8 pts/thread in
// registers. Exact f32 arithmetic (no FMA contraction) matching numpy order
// ((dx*dx+dy*dy)+dz*dz); strict-> argmax => first-occurrence tie-break.
// ---------------------------------------------------------------------------
__global__ __launch_bounds__(512) void fps_kernel(const float* __restrict__ xyz,
                                                  float* __restrict__ newxyz_f,
                                                  float* __restrict__ out){
  __shared__ float s_x[NPTS], s_y[NPTS], s_z[NPTS];
  __shared__ float s_rv[2][8];
  __shared__ int   s_ri[2][8];
  const int b = blockIdx.x, t = threadIdx.x;
  const float* Xb = xyz + (size_t)b*NPTS*3;
  float px[8], py[8], pz[8], dd[8];
  #pragma unroll
  for (int i=0;i<8;++i){
    int n = t*8+i;
    float x = Xb[n*3+0], y = Xb[n*3+1], z = Xb[n*3+2];
    px[i]=x; py[i]=y; pz[i]=z; dd[i]=1e10f;
    s_x[n]=x; s_y[n]=y; s_z[n]=z;
  }
  if (t==0){
    size_t o=(size_t)b*NPOINT*3;   // sample 0 is index 0 (scan emits prior carry)
    newxyz_f[o]=px[0]; newxyz_f[o+1]=py[0]; newxyz_f[o+2]=pz[0];
    out[o]=px[0]; out[o+1]=py[0]; out[o+2]=pz[0];
  }
  __syncthreads();
  float cx=s_x[0], cy=s_y[0], cz=s_z[0];
  const int lane = t&63, wid = t>>6;
  for (int s=1;s<NPOINT;++s){
    float bv=-1.0f; int bi=0;
    #pragma unroll
    for (int i=0;i<8;++i){
      float dx=__fsub_rn(px[i],cx), dy=__fsub_rn(py[i],cy), dz=__fsub_rn(pz[i],cz);
      float d=__fadd_rn(__fadd_rn(__fmul_rn(dx,dx),__fmul_rn(dy,dy)),__fmul_rn(dz,dz));
      float nd=fminf(dd[i],d); dd[i]=nd;
      if (nd>bv){ bv=nd; bi=t*8+i; }    // ascending i + strict > => lowest idx on tie
    }
    #pragma unroll
    for (int off=32; off>0; off>>=1){
      float ov=__shfl_down(bv,off,64);
      int   oi=__shfl_down(bi,off,64);
      if (ov>bv || (ov==bv && oi<bi)){ bv=ov; bi=oi; }
    }
    const int buf = s&1;
    if (lane==0){ s_rv[buf][wid]=bv; s_ri[buf][wid]=bi; }
    __syncthreads();
    float fv=s_rv[buf][0]; int fi=s_ri[buf][0];
    #pragma unroll
    for (int w=1;w<8;++w){
      float ov=s_rv[buf][w]; int oi=s_ri[buf][w];
      if (ov>fv || (ov==fv && oi<fi)){ fv=ov; fi=oi; }
    }
    cx=s_x[fi]; cy=s_y[fi]; cz=s_z[fi];
    if (t==0){
      size_t o=((size_t)b*NPOINT+s)*3;
      newxyz_f[o]=cx; newxyz_f[o+1]=cy; newxyz_f[o+2]=cz;
      out[o]=cx; out[o+1]=cy; out[o+2]=cz;
    }
    // no 2nd barrier: next iter writes the OTHER s_rv buffer; reaching that
    // write requires passing this barrier, which all waves' reads precede.
  }
}

// ---------------------------------------------------------------------------
// K2: Ball query. One wave per center; batch xyz staged in LDS. First NSAMPLE
// in-radius indices in ascending j (== sort semantics) via ballot + prefix
// popcount; pad with first index.
// ---------------------------------------------------------------------------
__global__ __launch_bounds__(256) void ballq_kernel(const float* __restrict__ xyz,
                                                    const float* __restrict__ newxyz_f,
                                                    int* __restrict__ ballidx){
  __shared__ float s_x[NPTS], s_y[NPTS], s_z[NPTS];
  __shared__ int s_list[4][NSAMPLE];
  const int b  = blockIdx.x >> 8;     // 256 s-groups per batch
  const int sg = blockIdx.x & 255;
  const int t = threadIdx.x;
  const float* Xb = xyz + (size_t)b*NPTS*3;
  for (int n=t;n<NPTS;n+=256){
    s_x[n]=Xb[n*3+0]; s_y[n]=Xb[n*3+1]; s_z[n]=Xb[n*3+2];
  }
  __syncthreads();
  const int lane = t&63, wid = t>>6;
  const int s = sg*4 + wid;
  size_t co = ((size_t)b*NPOINT+s)*3;
  const float cx=newxyz_f[co], cy=newxyz_f[co+1], cz=newxyz_f[co+2];
  const float R2 = 0.04f;             // f32(0.2**2), NEP-50 weak-scalar promotion
  int count = 0;
  for (int j0=0; j0<NPTS && count<NSAMPLE; j0+=64){
    int j=j0+lane;
    float dx=__fsub_rn(cx,s_x[j]), dy=__fsub_rn(cy,s_y[j]), dz=__fsub_rn(cz,s_z[j]);
    float sq=__fadd_rn(__fadd_rn(__fmul_rn(dx,dx),__fmul_rn(dy,dy)),__fmul_rn(dz,dz));
    bool in = !(sq > R2);
    unsigned long long m = __ballot(in);
    int before = __popcll(m & ((1ull<<lane)-1ull));
    int pos = count + before;
    if (in && pos < NSAMPLE) s_list[wid][pos] = j;
    count += __popcll(m);
  }
  int c = count < NSAMPLE ? count : NSAMPLE;   // >=1: center is in its own ball
  int first = s_list[wid][0];
  if (lane >= c && lane < NSAMPLE) s_list[wid][lane] = first;
  if (lane < NSAMPLE) ballidx[((size_t)b*NPOINT+s)*NSAMPLE + lane] = s_list[wid][lane];
}

// ---------------------------------------------------------------------------
// K3: layer 1 — gather + concat + (67 -> 64) matmul + bias -> h (bf16).
// REWRITE (R4 post-mortem): the old per-thread private gather was uncoalesced
// (64 scattered lines per wave-load -> 2.9 GB FETCH) and its private arrays
// were demoted to scratch (5.6 GB phantom WRITE). Now:
//  - block stages 128 gathered rows into LDS coalesced (16 lanes per 256-B
//    points row), xyz-norm channels appended; row stride 71 f32 (odd dword
//    count -> conflict-free column reads).
//  - grid is split over output halves (blockIdx&1): each thread computes
//    acc[16] only (~50 VGPR, no spill), weights broadcast from LDS (f32,
//    arithmetic identical to the passing version).
// ---------------------------------------------------------------------------
#define L1_STRIDE 71
__global__ __launch_bounds__(256,3) void layer1_kernel(const float* __restrict__ xyz,
    const float* __restrict__ points, const int* __restrict__ ballidx,
    const float* __restrict__ newxyz_f, const float* __restrict__ w0,
    const float* __restrict__ b0, unsigned short* __restrict__ h){
  __shared__ float s_w[67*32];            // [c][o_local], c: 0..63=points, 64..66=xyz
  __shared__ float s_b[32];
  __shared__ float s_x[128*L1_STRIDE];    // 128 rows x 71 (67 used)
  __shared__ int   s_j[128];
  const int t = threadIdx.x;
  const int tile = blockIdx.x >> 1;       // 4096 tiles of 128 rows
  const int half = blockIdx.x & 1;        // output channels [half*32, half*32+32)
  const int tileBase = tile*128;
  // weights: reorder channels (points first, xyz last)
  for (int i=t;i<67*32;i+=256){
    int c=i>>5, oL=i&31;
    int srcc = (c<64) ? (c+3) : (c-64);
    s_w[i] = w0[(half*32+oL)*67 + srcc];
  }
  if (t<32) s_b[t]=b0[half*32+t];
  if (t<128) s_j[t]=ballidx[tileBase+t];
  __syncthreads();
  // stage points rows: 8 sweeps x 16 rows, 16 lanes per row (float4 each)
  #pragma unroll
  for (int it=0; it<8; ++it){
    int r = it*16 + (t>>4);
    int row = tileBase + r;
    int bb = row >> 15;                   // 32768 rows per batch
    int j  = s_j[r];
    float4 pv = *(const float4*)(points + ((size_t)bb*NPTS + (size_t)j)*CPTS + (t&15)*4);
    float* xr = s_x + r*L1_STRIDE + (t&15)*4;
    xr[0]=pv.x; xr[1]=pv.y; xr[2]=pv.z; xr[3]=pv.w;
  }
  // stage xyz-norm channels 64..66
  if (t<128){
    int row = tileBase + t;
    int bs  = row >> 5;
    int bb  = bs >> 10;
    int j   = s_j[t];
    const float* xr = xyz + ((size_t)bb*NPTS + (size_t)j)*3;
    const float* cp = newxyz_f + (size_t)bs*3;
    float* xd = s_x + t*L1_STRIDE + 64;
    xd[0]=(xr[0]-cp[0])/0.2f; xd[1]=(xr[1]-cp[1])/0.2f; xd[2]=(xr[2]-cp[2])/0.2f;
  }
  __syncthreads();
  // compute: 2 threads per row (o-split 16/16), acc[16]
  const int r    = t & 127;
  const int osub = (t>>7)*16;
  const float* xp = s_x + r*L1_STRIDE;
  float acc[16];
  #pragma unroll
  for (int o=0;o<16;++o) acc[o]=0.0f;
  for (int c=0;c<67;++c){
    float xv = xp[c];
    const float4* wr=(const float4*)(s_w + c*32 + osub);
    #pragma unroll
    for (int q=0;q<4;++q){ float4 w=wr[q];
      acc[4*q+0]=fmaf(xv,w.x,acc[4*q+0]); acc[4*q+1]=fmaf(xv,w.y,acc[4*q+1]);
      acc[4*q+2]=fmaf(xv,w.z,acc[4*q+2]); acc[4*q+3]=fmaf(xv,w.w,acc[4*q+3]); }
  }
  uint4* od=(uint4*)(h + (size_t)(tileBase+r)*64 + half*32 + osub);
  #pragma unroll
  for (int q=0;q<2;++q){
    uint4 v;
    v.x=pack2(acc[8*q+0]+s_b[osub+8*q+0], acc[8*q+1]+s_b[osub+8*q+1]);
    v.y=pack2(acc[8*q+2]+s_b[osub+8*q+2], acc[8*q+3]+s_b[osub+8*q+3]);
    v.z=pack2(acc[8*q+4]+s_b[osub+8*q+4], acc[8*q+5]+s_b[osub+8*q+5]);
    v.w=pack2(acc[8*q+6]+s_b[osub+8*q+6], acc[8*q+7]+s_b[osub+8*q+7]);
    od[q]=v;
  }
}

// ---------------------------------------------------------------------------
// Stats over h (bf16, C=64): per-channel sum/sumsq. Wave reads 8 rows/iter as
// uint4 (1KB/wave-inst, fully coalesced); each lane owns 8 fixed channels.
// LDS block-reduce, then one atomicAdd pair per channel per block.
// ---------------------------------------------------------------------------
__global__ __launch_bounds__(256) void stats64_kernel(const unsigned short* __restrict__ h,
                                                      float* __restrict__ st){
  __shared__ float s_red[4][64][8], s_red2[4][64][8];
  const int t=threadIdx.x, lane=t&63, wid=t>>6;
  const int gw = blockIdx.x*4+wid;         // 512 blocks -> 0..2047 waves
  const int rsub = lane>>3;
  float sm[8], sq[8];
  #pragma unroll
  for (int j=0;j<8;++j){ sm[j]=0.f; sq[j]=0.f; }
  for (int it=0; it<32; ++it){
    size_t row = (size_t)gw*256 + it*8 + rsub;
    const uint4* p = (const uint4*)(h + row*64) + (lane&7);
    uint4 v = *p;
    uint32_t ds4[4]={v.x,v.y,v.z,v.w};
    #pragma unroll
    for (int dj=0;dj<4;++dj){
      float a=lo16(ds4[dj]), b2=hi16(ds4[dj]);
      sm[2*dj]+=a;   sq[2*dj]  =fmaf(a,a,sq[2*dj]);
      sm[2*dj+1]+=b2; sq[2*dj+1]=fmaf(b2,b2,sq[2*dj+1]);
    }
  }
  #pragma unroll
  for (int j=0;j<8;++j){ s_red[wid][lane][j]=sm[j]; s_red2[wid][lane][j]=sq[j]; }
  __syncthreads();
  if (t<64){
    // channel t: lanes l with (l&7)==t>>3, element t&7
    float ts=0.f,tq=0.f;
    #pragma unroll
    for (int w=0;w<4;++w)
      #pragma unroll
      for (int m=0;m<8;++m){ int l=(t>>3)+8*m; ts+=s_red[w][l][t&7]; tq+=s_red2[w][l][t&7]; }
    atomicAdd(&st[t*2], ts); atomicAdd(&st[t*2+1], tq);
  }
}

// ---------------------------------------------------------------------------
// K4: layer 2 — BN(stats0)+ReLU on the fly, (64 -> 64) matmul + bias, written
// IN PLACE over the same row. Row kept packed in 32 regs across both
// 32-channel passes.
// ---------------------------------------------------------------------------
__global__ __launch_bounds__(256,3) void layer2_kernel(unsigned short* __restrict__ h,
    const float* __restrict__ st, const float* __restrict__ g,
    const float* __restrict__ be, const float* __restrict__ w1,
    const float* __restrict__ b1){
  __shared__ float s_w[64*64];
  __shared__ float s_b[64], s_scale[64], s_shift[64];
  const int t=threadIdx.x;
  for (int i=t;i<64*64;i+=256){ int c=i>>6, o=i&63; s_w[i]=w1[o*64+c]; }
  if (t<64){
    s_b[t]=b1[t];
    float mu=st[t*2]*(1.0f/NROWS);
    float var=st[t*2+1]*(1.0f/NROWS)-mu*mu;
    float inv=1.0f/sqrtf(var+1e-5f);
    s_scale[t]=inv*g[t]; s_shift[t]=be[t]-mu*inv*g[t];
  }
  __syncthreads();
  const size_t row = (size_t)blockIdx.x*256+t;
  unsigned short* hr = h + row*64;
  uint32_t rowd[32];
  const uint4* hv=(const uint4*)hr;
  #pragma unroll
  for (int cc=0;cc<8;++cc){ uint4 rv=hv[cc];
    rowd[4*cc]=rv.x; rowd[4*cc+1]=rv.y; rowd[4*cc+2]=rv.z; rowd[4*cc+3]=rv.w; }
  #pragma unroll 1
  for (int pass=0; pass<2; ++pass){
    const int po = pass*32;
    float acc[32];
    #pragma unroll
    for (int o=0;o<32;++o) acc[o]=0.0f;
    #pragma unroll
    for (int c=0;c<64;++c){
      uint32_t d=rowd[c>>1];
      float x=(c&1)? hi16(d):lo16(d);
      x=fmaxf(fmaf(x,s_scale[c],s_shift[c]),0.0f);
      const float4* wr=(const float4*)(s_w + c*64 + po);
      #pragma unroll
      for (int q=0;q<8;++q){ float4 w=wr[q];
        acc[4*q+0]=fmaf(x,w.x,acc[4*q+0]); acc[4*q+1]=fmaf(x,w.y,acc[4*q+1]);
        acc[4*q+2]=fmaf(x,w.z,acc[4*q+2]); acc[4*q+3]=fmaf(x,w.w,acc[4*q+3]); }
    }
    uint4* od=(uint4*)(hr + po);
    #pragma unroll
    for (int q=0;q<4;++q){
      uint4 v;
      v.x=pack2(acc[8*q+0]+s_b[po+8*q+0], acc[8*q+1]+s_b[po+8*q+1]);
      v.y=pack2(acc[8*q+2]+s_b[po+8*q+2], acc[8*q+3]+s_b[po+8*q+3]);
      v.z=pack2(acc[8*q+4]+s_b[po+8*q+4], acc[8*q+5]+s_b[po+8*q+5]);
      v.w=pack2(acc[8*q+6]+s_b[po+8*q+6], acc[8*q+7]+s_b[po+8*q+7]);
      od[q]=v;
    }
  }
}

// ---------------------------------------------------------------------------
// K5: layer 3 fused — BN(stats1)+ReLU, (64 -> 128) matmul + bias, per-s
// max/min over K=32 (h3 never materialized) + BN3 stats accumulation.
// Block 256 = 4 waves; wave owns 8 s-groups; lane = (k, half-of-channels).
// Channel work split into two 32-wide passes (acc[32]); row in rowd[32] regs.
// Per-wave LDS tile [32][136] bf16 transposes k->columns for the reduction.
// ---------------------------------------------------------------------------
__global__ __launch_bounds__(256,3) void layer3mm_kernel(const unsigned short* __restrict__ h,
    const float* __restrict__ st, const float* __restrict__ g,
    const float* __restrict__ be, const float* __restrict__ w2,
    const float* __restrict__ b2, float* __restrict__ mm, float* __restrict__ st2){
  __shared__ unsigned short s_w[64*128];        // 16KB  s_w[c*128+o]=bf16(w2[o][c])
  __shared__ unsigned short s_tile[4][32*136];  // 34816B, +8 u16 row pad
  __shared__ float s_scale[64], s_shift[64], s_b2[128];
  __shared__ float s_sum[4][128], s_sq[4][128]; // 4KB
  const int t=threadIdx.x, lane=t&63, wid=t>>6;
  for (int i=t;i<64*128;i+=256){ int c=i>>7, o=i&127; s_w[i]=f2bf(w2[o*64+c]); }
  if (t<64){
    float mu=st[t*2]*(1.0f/NROWS);
    float var=st[t*2+1]*(1.0f/NROWS)-mu*mu;
    float inv=1.0f/sqrtf(var+1e-5f);
    s_scale[t]=inv*g[t]; s_shift[t]=be[t]-mu*inv*g[t];
  }
  if (t<128) s_b2[t]=b2[t];
  __syncthreads();
  const int k=lane&31, half=lane>>5, oo=half*64;
  unsigned short* tile = s_tile[wid];
  const int waveG = blockIdx.x*4+wid;           // 512 blocks -> 0..2047
  float sumA=0.f,sqA=0.f,sumB=0.f,sqB=0.f;
  for (int i2=0;i2<8;++i2){
    const int s = waveG*8 + i2;
    const unsigned short* hp = h + ((size_t)s*32 + (size_t)k)*64;
    uint32_t rowd[32];
    const uint4* hv=(const uint4*)hp;
    #pragma unroll
    for (int cc=0;cc<8;++cc){ uint4 rv=hv[cc];
      rowd[4*cc]=rv.x; rowd[4*cc+1]=rv.y; rowd[4*cc+2]=rv.z; rowd[4*cc+3]=rv.w; }
    #pragma unroll 1
    for (int pass=0; pass<2; ++pass){
      const int po = pass*32;
      float acc[32];
      #pragma unroll
      for (int o=0;o<32;++o) acc[o]=0.0f;
      #pragma unroll
      for (int c=0;c<64;++c){
        uint32_t d=rowd[c>>1];
        float x=(c&1)? hi16(d):lo16(d);
        x=fmaxf(fmaf(x,s_scale[c],s_shift[c]),0.0f);
        const uint4* wr=(const uint4*)(s_w + (size_t)c*128 + oo + po);
        #pragma unroll
        for (int q=0;q<4;++q){
          uint4 wu=wr[q];
          acc[8*q+0]=fmaf(x,lo16(wu.x),acc[8*q+0]); acc[8*q+1]=fmaf(x,hi16(wu.x),acc[8*q+1]);
          acc[8*q+2]=fmaf(x,lo16(wu.y),acc[8*q+2]); acc[8*q+3]=fmaf(x,hi16(wu.y),acc[8*q+3]);
          acc[8*q+4]=fmaf(x,lo16(wu.z),acc[8*q+4]); acc[8*q+5]=fmaf(x,hi16(wu.z),acc[8*q+5]);
          acc[8*q+6]=fmaf(x,lo16(wu.w),acc[8*q+6]); acc[8*q+7]=fmaf(x,hi16(wu.w),acc[8*q+7]);
        }
      }
      // + bias, pack to wave tile row k, channels [oo+po, oo+po+32)
      uint4* tw=(uint4*)(tile + (size_t)k*136 + oo + po);
      #pragma unroll
      for (int q=0;q<4;++q){
        uint4 v;
        v.x=pack2(acc[8*q+0]+s_b2[oo+po+8*q+0], acc[8*q+1]+s_b2[oo+po+8*q+1]);
        v.y=pack2(acc[8*q+2]+s_b2[oo+po+8*q+2], acc[8*q+3]+s_b2[oo+po+8*q+3]);
        v.z=pack2(acc[8*q+4]+s_b2[oo+po+8*q+4], acc[8*q+5]+s_b2[oo+po+8*q+5]);
        v.w=pack2(acc[8*q+6]+s_b2[oo+po+8*q+6], acc[8*q+7]+s_b2[oo+po+8*q+7]);
        tw[q]=v;
      }
    }
    // wave-coherent LDS (in-order DS pipe, lockstep wave64): no barrier.
    // Column reduce: lane owns channels (lane, lane+64) over k=0..31.
    float mxA=-3e38f, mnA=3e38f, mxB=-3e38f, mnB=3e38f;
    float sA=0.f,qA=0.f,sB=0.f,qB=0.f;
    #pragma unroll
    for (int kk=0;kk<32;++kk){
      float a = bf2f(tile[kk*136 + lane]);
      float b3= bf2f(tile[kk*136 + lane + 64]);
      mxA=fmaxf(mxA,a); mnA=fminf(mnA,a); sA+=a; qA=fmaf(a,a,qA);
      mxB=fmaxf(mxB,b3); mnB=fminf(mnB,b3); sB+=b3; qB=fmaf(b3,b3,qB);
    }
    float* mp = mm + (size_t)s*256;
    mp[lane]      = mxA; mp[lane+64]  = mxB;    // max plane
    mp[128+lane]  = mnA; mp[192+lane] = mnB;    // min plane
    sumA+=sA; sqA+=qA; sumB+=sB; sqB+=qB;
  }
  s_sum[wid][lane]=sumA; s_sum[wid][lane+64]=sumB;
  s_sq [wid][lane]=sqA;  s_sq [wid][lane+64]=sqB;
  __syncthreads();
  if (t<128){
    float ts=0.f,tq=0.f;
    #pragma unroll
    for (int w=0;w<4;++w){ ts+=s_sum[w][t]; tq+=s_sq[w][t]; }
    atomicAdd(&st2[t*2], ts); atomicAdd(&st2[t*2+1], tq);
  }
}

// ---------------------------------------------------------------------------
// K6: BN(stats2) on max (or min if scale<0) + ReLU -> new_points (f32).
// ---------------------------------------------------------------------------
__global__ __launch_bounds__(256) void final_kernel(const float* __restrict__ mm,
    const float* __restrict__ st, const float* __restrict__ g,
    const float* __restrict__ be, float* __restrict__ out){
  __shared__ float s_scale[128], s_shift[128];
  const int t=threadIdx.x;
  if (t<128){
    float mu=st[t*2]*(1.0f/NROWS);
    float var=st[t*2+1]*(1.0f/NROWS)-mu*mu;
    float inv=1.0f/sqrtf(var+1e-5f);
    s_scale[t]=inv*g[t]; s_shift[t]=be[t]-mu*inv*g[t];
  }
  __syncthreads();
  const int idx = blockIdx.x*256+t;       // bs*128 + ch
  const int ch = idx & 127, bs = idx >> 7;
  float sc=s_scale[ch];
  float v = (sc>=0.f)? mm[(size_t)bs*256+ch] : mm[(size_t)bs*256+128+ch];
  out[(size_t)NB*NPOINT*3 + idx] = fmaxf(fmaf(v,sc,s_shift[ch]),0.0f);
}

// ---------------------------------------------------------------------------
extern "C" void kernel_launch(void* const* d_in, const int* in_sizes, int n_in,
                              void* d_out, int out_size, void* d_ws, size_t ws_size,
                              hipStream_t stream) {
  const float* xyz    = (const float*)d_in[0];
  const float* points = (const float*)d_in[1];
  const float* w0 = (const float*)d_in[2];
  const float* b0 = (const float*)d_in[3];
  const float* g0 = (const float*)d_in[4];
  const float* be0= (const float*)d_in[5];
  const float* w1 = (const float*)d_in[6];
  const float* b1 = (const float*)d_in[7];
  const float* g1 = (const float*)d_in[8];
  const float* be1= (const float*)d_in[9];
  const float* w2 = (const float*)d_in[10];
  const float* b2 = (const float*)d_in[11];
  const float* g2 = (const float*)d_in[12];
  const float* be2= (const float*)d_in[13];
  float* out = (float*)d_out;             // f32 output per reference dtype
  char* ws = (char*)d_ws;

  // ws layout (84 MiB total):
  //   [0,        196608)    newxyz_f (16,1024,3) f32
  //   [196608,   2293760)   ballidx  (16,1024,32) i32
  //   [2293760,  2296832)   stats: 3 slots x 256 f32 {sum,sumsq interleaved}
  //   [4 MiB,    20 MiB)    mm: (16384, {max,min}, 128) f32
  //   [20 MiB,   84 MiB)    h: (524288, 64) bf16 — h1, then h2 in place
  float* newxyz_f = (float*)(ws);
  int*   ballidx  = (int*)(ws + 196608);
  float* stats    = (float*)(ws + 2293760);
  float* mm       = (float*)(ws + 4194304);
  unsigned short* h = (unsigned short*)(ws + 20971520);

  hipMemsetAsync(stats, 0, 3072, stream);
  hipLaunchKernelGGL(fps_kernel,     dim3(NB),   dim3(512), 0, stream, xyz, newxyz_f, out);
  hipLaunchKernelGGL(ballq_kernel,   dim3(4096), dim3(256), 0, stream, xyz, newxyz_f, ballidx);
  hipLaunchKernelGGL(layer1_kernel,  dim3(8192), dim3(256), 0, stream,
                     xyz, points, ballidx, newxyz_f, w0, b0, h);
  hipLaunchKernelGGL(stats64_kernel, dim3(512),  dim3(256), 0, stream, h, stats + 0);
  hipLaunchKernelGGL(layer2_kernel,  dim3(2048), dim3(256), 0, stream,
                     h, stats + 0, g0, be0, w1, b1);
  hipLaunchKernelGGL(stats64_kernel, dim3(512),  dim3(256), 0, stream, h, stats + 256);
  hipLaunchKernelGGL(layer3mm_kernel,dim3(512),  dim3(256), 0, stream,
                     h, stats + 256, g1, be1, w2, b2, mm, stats + 512);
  hipLaunchKernelGGL(final_kernel,   dim3(8192), dim3(256), 0, stream,
                     mm, stats + 512, g2, be2, out);
}

// Round 6
// 2151.747 us; speedup vs baseline: 2.8302x; 1.8540x over previous
//
#include <hip/hip_runtime.h>
#include <stdint.h>

// Problem constants
#define NB      16
#define NPTS    4096
#define CPTS    64
#define NPOINT  1024
#define NSAMPLE 32
#define NROWS   (NB*NPOINT*NSAMPLE)   // 524288 rows of (b,s,k)

// f32 -> bf16 (RNE) and bf16 -> f32 (intermediates only; in/out are f32)
__device__ __forceinline__ unsigned short f2bf(float f){
  uint32_t u = __float_as_uint(f);
  uint32_t r = u + 0x7fffu + ((u>>16)&1u);
  return (unsigned short)(r>>16);
}
__device__ __forceinline__ float bf2f(unsigned short u){ return __uint_as_float(((uint32_t)u)<<16); }
__device__ __forceinline__ float lo16(uint32_t d){ return __uint_as_float(d<<16); }
__device__ __forceinline__ float hi16(uint32_t d){ return __uint_as_float(d & 0xffff0000u); }
__device__ __forceinline__ uint32_t pack2(float a, float b){ return ((uint32_t)f2bf(b)<<16) | (uint32_t)f2bf(a); }

// ---------------------------------------------------------------------------
// K1: Farthest point sampling. 1 block/batch, 512 threads, 8 pts/thread in
// registers. Exact f32 arithmetic (no FMA contraction) matching numpy order
// ((dx*dx+dy*dy)+dz*dz); strict-> argmax => first-occurrence tie-break.
// ---------------------------------------------------------------------------
__global__ __launch_bounds__(512) void fps_kernel(const float* __restrict__ xyz,
                                                  float* __restrict__ newxyz_f,
                                                  float* __restrict__ out){
  __shared__ float s_x[NPTS], s_y[NPTS], s_z[NPTS];
  __shared__ float s_rv[2][8];
  __shared__ int   s_ri[2][8];
  const int b = blockIdx.x, t = threadIdx.x;
  const float* Xb = xyz + (size_t)b*NPTS*3;
  float px[8], py[8], pz[8], dd[8];
  #pragma unroll
  for (int i=0;i<8;++i){
    int n = t*8+i;
    float x = Xb[n*3+0], y = Xb[n*3+1], z = Xb[n*3+2];
    px[i]=x; py[i]=y; pz[i]=z; dd[i]=1e10f;
    s_x[n]=x; s_y[n]=y; s_z[n]=z;
  }
  if (t==0){
    size_t o=(size_t)b*NPOINT*3;   // sample 0 is index 0 (scan emits prior carry)
    newxyz_f[o]=px[0]; newxyz_f[o+1]=py[0]; newxyz_f[o+2]=pz[0];
    out[o]=px[0]; out[o+1]=py[0]; out[o+2]=pz[0];
  }
  __syncthreads();
  float cx=s_x[0], cy=s_y[0], cz=s_z[0];
  const int lane = t&63, wid = t>>6;
  for (int s=1;s<NPOINT;++s){
    float bv=-1.0f; int bi=0;
    #pragma unroll
    for (int i=0;i<8;++i){
      float dx=__fsub_rn(px[i],cx), dy=__fsub_rn(py[i],cy), dz=__fsub_rn(pz[i],cz);
      float d=__fadd_rn(__fadd_rn(__fmul_rn(dx,dx),__fmul_rn(dy,dy)),__fmul_rn(dz,dz));
      float nd=fminf(dd[i],d); dd[i]=nd;
      if (nd>bv){ bv=nd; bi=t*8+i; }    // ascending i + strict > => lowest idx on tie
    }
    #pragma unroll
    for (int off=32; off>0; off>>=1){
      float ov=__shfl_down(bv,off,64);
      int   oi=__shfl_down(bi,off,64);
      if (ov>bv || (ov==bv && oi<bi)){ bv=ov; bi=oi; }
    }
    const int buf = s&1;
    if (lane==0){ s_rv[buf][wid]=bv; s_ri[buf][wid]=bi; }
    __syncthreads();
    float fv=s_rv[buf][0]; int fi=s_ri[buf][0];
    #pragma unroll
    for (int w=1;w<8;++w){
      float ov=s_rv[buf][w]; int oi=s_ri[buf][w];
      if (ov>fv || (ov==fv && oi<fi)){ fv=ov; fi=oi; }
    }
    cx=s_x[fi]; cy=s_y[fi]; cz=s_z[fi];
    if (t==0){
      size_t o=((size_t)b*NPOINT+s)*3;
      newxyz_f[o]=cx; newxyz_f[o+1]=cy; newxyz_f[o+2]=cz;
      out[o]=cx; out[o+1]=cy; out[o+2]=cz;
    }
    // no 2nd barrier: next iter writes the OTHER s_rv buffer; reaching that
    // write requires passing this barrier, which all waves' reads precede.
  }
}

// ---------------------------------------------------------------------------
// K2: Ball query. One wave per center; batch xyz staged in LDS. First NSAMPLE
// in-radius indices in ascending j (== sort semantics) via ballot + prefix
// popcount; pad with first index.
// ---------------------------------------------------------------------------
__global__ __launch_bounds__(256) void ballq_kernel(const float* __restrict__ xyz,
                                                    const float* __restrict__ newxyz_f,
                                                    int* __restrict__ ballidx){
  __shared__ float s_x[NPTS], s_y[NPTS], s_z[NPTS];
  __shared__ int s_list[4][NSAMPLE];
  const int b  = blockIdx.x >> 8;     // 256 s-groups per batch
  const int sg = blockIdx.x & 255;
  const int t = threadIdx.x;
  const float* Xb = xyz + (size_t)b*NPTS*3;
  for (int n=t;n<NPTS;n+=256){
    s_x[n]=Xb[n*3+0]; s_y[n]=Xb[n*3+1]; s_z[n]=Xb[n*3+2];
  }
  __syncthreads();
  const int lane = t&63, wid = t>>6;
  const int s = sg*4 + wid;
  size_t co = ((size_t)b*NPOINT+s)*3;
  const float cx=newxyz_f[co], cy=newxyz_f[co+1], cz=newxyz_f[co+2];
  const float R2 = 0.04f;             // f32(0.2**2), NEP-50 weak-scalar promotion
  int count = 0;
  for (int j0=0; j0<NPTS && count<NSAMPLE; j0+=64){
    int j=j0+lane;
    float dx=__fsub_rn(cx,s_x[j]), dy=__fsub_rn(cy,s_y[j]), dz=__fsub_rn(cz,s_z[j]);
    float sq=__fadd_rn(__fadd_rn(__fmul_rn(dx,dx),__fmul_rn(dy,dy)),__fmul_rn(dz,dz));
    bool in = !(sq > R2);
    unsigned long long m = __ballot(in);
    int before = __popcll(m & ((1ull<<lane)-1ull));
    int pos = count + before;
    if (in && pos < NSAMPLE) s_list[wid][pos] = j;
    count += __popcll(m);
  }
  int c = count < NSAMPLE ? count : NSAMPLE;   // >=1: center is in its own ball
  int first = s_list[wid][0];
  if (lane >= c && lane < NSAMPLE) s_list[wid][lane] = first;
  if (lane < NSAMPLE) ballidx[((size_t)b*NPOINT+s)*NSAMPLE + lane] = s_list[wid][lane];
}

// ---------------------------------------------------------------------------
// K3: layer 1 — gather + concat + (67 -> 64) matmul + bias -> h (bf16).
// LDS-staged coalesced gather; 2 threads per row, acc[16] (no private arrays
// with dynamic indexing -> no scratch demotion).
// ---------------------------------------------------------------------------
#define L1_STRIDE 71
__global__ __launch_bounds__(256,3) void layer1_kernel(const float* __restrict__ xyz,
    const float* __restrict__ points, const int* __restrict__ ballidx,
    const float* __restrict__ newxyz_f, const float* __restrict__ w0,
    const float* __restrict__ b0, unsigned short* __restrict__ h){
  __shared__ float s_w[67*32];            // [c][o_local], c: 0..63=points, 64..66=xyz
  __shared__ float s_b[32];
  __shared__ float s_x[128*L1_STRIDE];    // 128 rows x 71 (67 used)
  __shared__ int   s_j[128];
  const int t = threadIdx.x;
  const int tile = blockIdx.x >> 1;       // 4096 tiles of 128 rows
  const int half = blockIdx.x & 1;        // output channels [half*32, half*32+32)
  const int tileBase = tile*128;
  for (int i=t;i<67*32;i+=256){
    int c=i>>5, oL=i&31;
    int srcc = (c<64) ? (c+3) : (c-64);
    s_w[i] = w0[(half*32+oL)*67 + srcc];
  }
  if (t<32) s_b[t]=b0[half*32+t];
  if (t<128) s_j[t]=ballidx[tileBase+t];
  __syncthreads();
  #pragma unroll
  for (int it=0; it<8; ++it){
    int r = it*16 + (t>>4);
    int row = tileBase + r;
    int bb = row >> 15;                   // 32768 rows per batch
    int j  = s_j[r];
    float4 pv = *(const float4*)(points + ((size_t)bb*NPTS + (size_t)j)*CPTS + (t&15)*4);
    float* xr = s_x + r*L1_STRIDE + (t&15)*4;
    xr[0]=pv.x; xr[1]=pv.y; xr[2]=pv.z; xr[3]=pv.w;
  }
  if (t<128){
    int row = tileBase + t;
    int bs  = row >> 5;
    int bb  = bs >> 10;
    int j   = s_j[t];
    const float* xr = xyz + ((size_t)bb*NPTS + (size_t)j)*3;
    const float* cp = newxyz_f + (size_t)bs*3;
    float* xd = s_x + t*L1_STRIDE + 64;
    xd[0]=(xr[0]-cp[0])/0.2f; xd[1]=(xr[1]-cp[1])/0.2f; xd[2]=(xr[2]-cp[2])/0.2f;
  }
  __syncthreads();
  const int r    = t & 127;
  const int osub = (t>>7)*16;
  const float* xp = s_x + r*L1_STRIDE;
  float acc[16];
  #pragma unroll
  for (int o=0;o<16;++o) acc[o]=0.0f;
  for (int c=0;c<67;++c){
    float xv = xp[c];
    const float4* wr=(const float4*)(s_w + c*32 + osub);
    #pragma unroll
    for (int q=0;q<4;++q){ float4 w=wr[q];
      acc[4*q+0]=fmaf(xv,w.x,acc[4*q+0]); acc[4*q+1]=fmaf(xv,w.y,acc[4*q+1]);
      acc[4*q+2]=fmaf(xv,w.z,acc[4*q+2]); acc[4*q+3]=fmaf(xv,w.w,acc[4*q+3]); }
  }
  uint4* od=(uint4*)(h + (size_t)(tileBase+r)*64 + half*32 + osub);
  #pragma unroll
  for (int q=0;q<2;++q){
    uint4 v;
    v.x=pack2(acc[8*q+0]+s_b[osub+8*q+0], acc[8*q+1]+s_b[osub+8*q+1]);
    v.y=pack2(acc[8*q+2]+s_b[osub+8*q+2], acc[8*q+3]+s_b[osub+8*q+3]);
    v.z=pack2(acc[8*q+4]+s_b[osub+8*q+4], acc[8*q+5]+s_b[osub+8*q+5]);
    v.w=pack2(acc[8*q+6]+s_b[osub+8*q+6], acc[8*q+7]+s_b[osub+8*q+7]);
    od[q]=v;
  }
}

// ---------------------------------------------------------------------------
// Stats over h (bf16, C=64): per-channel sum/sumsq, coalesced uint4 reads,
// LDS block-reduce, one atomicAdd pair per channel per block.
// ---------------------------------------------------------------------------
__global__ __launch_bounds__(256) void stats64_kernel(const unsigned short* __restrict__ h,
                                                      float* __restrict__ st){
  __shared__ float s_red[4][64][8], s_red2[4][64][8];
  const int t=threadIdx.x, lane=t&63, wid=t>>6;
  const int gw = blockIdx.x*4+wid;         // 512 blocks -> 0..2047 waves
  const int rsub = lane>>3;
  float sm[8], sq[8];
  #pragma unroll
  for (int j=0;j<8;++j){ sm[j]=0.f; sq[j]=0.f; }
  for (int it=0; it<32; ++it){
    size_t row = (size_t)gw*256 + it*8 + rsub;
    const uint4* p = (const uint4*)(h + row*64) + (lane&7);
    uint4 v = *p;
    uint32_t ds4[4]={v.x,v.y,v.z,v.w};
    #pragma unroll
    for (int dj=0;dj<4;++dj){
      float a=lo16(ds4[dj]), b2=hi16(ds4[dj]);
      sm[2*dj]+=a;   sq[2*dj]  =fmaf(a,a,sq[2*dj]);
      sm[2*dj+1]+=b2; sq[2*dj+1]=fmaf(b2,b2,sq[2*dj+1]);
    }
  }
  #pragma unroll
  for (int j=0;j<8;++j){ s_red[wid][lane][j]=sm[j]; s_red2[wid][lane][j]=sq[j]; }
  __syncthreads();
  if (t<64){
    float ts=0.f,tq=0.f;
    #pragma unroll
    for (int w=0;w<4;++w)
      #pragma unroll
      for (int m=0;m<8;++m){ int l=(t>>3)+8*m; ts+=s_red[w][l][t&7]; tq+=s_red2[w][l][t&7]; }
    atomicAdd(&st[t*2], ts); atomicAdd(&st[t*2+1], tq);
  }
}

// ---------------------------------------------------------------------------
// K4: layer 2 — (64 -> 64) matmul + bias, in place.  REWRITE (R5 post-mortem:
// rowd/acc arrays under "#pragma unroll 1" were demoted to scratch -> 7.3 GB
// phantom HBM traffic, VALUBusy 4%).  Now: BN(stats0)+ReLU applied while
// staging 128 rows into an LDS tile (stride 65 -> conflict-free column
// reads); 2 threads per row compute acc[32] fully unrolled (constant
// indices, no private arrays).  Weight reads are wave-uniform broadcasts.
// ---------------------------------------------------------------------------
__global__ __launch_bounds__(256,3) void layer2_kernel(unsigned short* __restrict__ h,
    const float* __restrict__ st, const float* __restrict__ g,
    const float* __restrict__ be, const float* __restrict__ w1,
    const float* __restrict__ b1){
  __shared__ float s_w[64*64];            // 16 KB  [c][o]
  __shared__ float s_x[128*65];           // 33.3 KB
  __shared__ float s_b[64], s_scale[64], s_shift[64];
  const int t=threadIdx.x;
  const int tileBase = blockIdx.x*128;    // 4096 blocks
  for (int i=t;i<64*64;i+=256){ int c=i>>6, o=i&63; s_w[i]=w1[o*64+c]; }
  if (t<64){
    s_b[t]=b1[t];
    float mu=st[t*2]*(1.0f/NROWS);
    float var=st[t*2+1]*(1.0f/NROWS)-mu*mu;
    float inv=1.0f/sqrtf(var+1e-5f);
    s_scale[t]=inv*g[t]; s_shift[t]=be[t]-mu*inv*g[t];
  }
  __syncthreads();
  // stage 128 rows, BN+ReLU at stage time. 1024 seg-tasks, 4 sweeps.
  #pragma unroll
  for (int it=0; it<4; ++it){
    int idx = it*256 + t;
    int r = idx>>3, seg = idx&7;
    uint4 v = *((const uint4*)(h + (size_t)(tileBase+r)*64) + seg);
    float* xd = s_x + r*65 + seg*8;
    uint32_t ds4[4]={v.x,v.y,v.z,v.w};
    #pragma unroll
    for (int dj=0;dj<4;++dj){
      int c = seg*8 + dj*2;
      xd[dj*2+0]=fmaxf(fmaf(lo16(ds4[dj]),s_scale[c],  s_shift[c]),  0.0f);
      xd[dj*2+1]=fmaxf(fmaf(hi16(ds4[dj]),s_scale[c+1],s_shift[c+1]),0.0f);
    }
  }
  __syncthreads();
  const int r    = t & 127;
  const int osub = (t>>7)*32;
  const float* xp = s_x + r*65;
  float acc[32];
  #pragma unroll
  for (int o=0;o<32;++o) acc[o]=0.0f;
  for (int c=0;c<64;++c){
    float xv = xp[c];
    const float4* wr=(const float4*)(s_w + c*64 + osub);
    #pragma unroll
    for (int q=0;q<8;++q){ float4 w=wr[q];
      acc[4*q+0]=fmaf(xv,w.x,acc[4*q+0]); acc[4*q+1]=fmaf(xv,w.y,acc[4*q+1]);
      acc[4*q+2]=fmaf(xv,w.z,acc[4*q+2]); acc[4*q+3]=fmaf(xv,w.w,acc[4*q+3]); }
  }
  // in-place write: all reads of this block's rows completed before barrier.
  uint4* od=(uint4*)(h + (size_t)(tileBase+r)*64 + osub);
  #pragma unroll
  for (int q=0;q<4;++q){
    uint4 v;
    v.x=pack2(acc[8*q+0]+s_b[osub+8*q+0], acc[8*q+1]+s_b[osub+8*q+1]);
    v.y=pack2(acc[8*q+2]+s_b[osub+8*q+2], acc[8*q+3]+s_b[osub+8*q+3]);
    v.z=pack2(acc[8*q+4]+s_b[osub+8*q+4], acc[8*q+5]+s_b[osub+8*q+5]);
    v.w=pack2(acc[8*q+6]+s_b[osub+8*q+6], acc[8*q+7]+s_b[osub+8*q+7]);
    od[q]=v;
  }
}

// ---------------------------------------------------------------------------
// K5: layer 3 fused — BN(stats1)+ReLU (at stage time), (64 -> 128) matmul +
// bias, per-s max/min over K=32 + BN3 partial sums.  One 32-row s-group per
// block (16384 blocks).  x tile stride 65; out tile f32 stride 133 (5 mod 32,
// conflict-free).  8 threads per row x acc[16]; no private arrays.
// Partial sums go to part[block][256] (atomic-free), reduced by K5b.
// ---------------------------------------------------------------------------
__global__ __launch_bounds__(256,3) void layer3mm_kernel(const unsigned short* __restrict__ h,
    const float* __restrict__ st, const float* __restrict__ g,
    const float* __restrict__ be, const float* __restrict__ w2,
    const float* __restrict__ b2, float* __restrict__ mm, float* __restrict__ part){
  __shared__ unsigned short s_w[64*128];  // 16 KB  s_w[c*128+o]=bf16(w2[o][c])
  __shared__ float s_x[32*65];            // 8.3 KB
  __shared__ float s_o[32*133];           // 17 KB
  __shared__ float s_scale[64], s_shift[64], s_b2[128];
  const int t=threadIdx.x;
  const int sgBase = blockIdx.x*32;       // row base of this s-group
  for (int i=t;i<64*128;i+=256){ int c=i>>7, o=i&127; s_w[i]=f2bf(w2[o*64+c]); }
  if (t<64){
    float mu=st[t*2]*(1.0f/NROWS);
    float var=st[t*2+1]*(1.0f/NROWS)-mu*mu;
    float inv=1.0f/sqrtf(var+1e-5f);
    s_scale[t]=inv*g[t]; s_shift[t]=be[t]-mu*inv*g[t];
  }
  if (t<128) s_b2[t]=b2[t];
  __syncthreads();
  // stage 32 rows (exactly 256 seg-tasks), BN+ReLU applied here
  {
    int r = t>>3, seg = t&7;
    uint4 v = *((const uint4*)(h + (size_t)(sgBase+r)*64) + seg);
    float* xd = s_x + r*65 + seg*8;
    uint32_t ds4[4]={v.x,v.y,v.z,v.w};
    #pragma unroll
    for (int dj=0;dj<4;++dj){
      int c = seg*8 + dj*2;
      xd[dj*2+0]=fmaxf(fmaf(lo16(ds4[dj]),s_scale[c],  s_shift[c]),  0.0f);
      xd[dj*2+1]=fmaxf(fmaf(hi16(ds4[dj]),s_scale[c+1],s_shift[c+1]),0.0f);
    }
  }
  __syncthreads();
  // compute: 8 threads per row, 16 out-channels each
  {
    const int r    = t & 31;
    const int osub = (t>>5)*16;
    const float* xp = s_x + r*65;
    float acc[16];
    #pragma unroll
    for (int o=0;o<16;++o) acc[o]=0.0f;
    for (int c=0;c<64;++c){
      float xv = xp[c];
      const uint4* wr=(const uint4*)(s_w + c*128 + osub);
      #pragma unroll
      for (int q=0;q<2;++q){
        uint4 wu=wr[q];
        acc[8*q+0]=fmaf(xv,lo16(wu.x),acc[8*q+0]); acc[8*q+1]=fmaf(xv,hi16(wu.x),acc[8*q+1]);
        acc[8*q+2]=fmaf(xv,lo16(wu.y),acc[8*q+2]); acc[8*q+3]=fmaf(xv,hi16(wu.y),acc[8*q+3]);
        acc[8*q+4]=fmaf(xv,lo16(wu.z),acc[8*q+4]); acc[8*q+5]=fmaf(xv,hi16(wu.z),acc[8*q+5]);
        acc[8*q+6]=fmaf(xv,lo16(wu.w),acc[8*q+6]); acc[8*q+7]=fmaf(xv,hi16(wu.w),acc[8*q+7]);
      }
    }
    float* op = s_o + r*133 + osub;
    #pragma unroll
    for (int o=0;o<16;++o) op[o] = acc[o] + s_b2[osub+o];
  }
  __syncthreads();
  // reduce over k=0..31 per channel: max/min (for final BN+relu+max) + sum/sq
  if (t<128){
    float mx=-3e38f, mn=3e38f, sm=0.f, sq=0.f;
    #pragma unroll
    for (int r=0;r<32;++r){
      float v = s_o[r*133 + t];
      mx=fmaxf(mx,v); mn=fminf(mn,v); sm+=v; sq=fmaf(v,v,sq);
    }
    float* mp = mm + (size_t)blockIdx.x*256;
    mp[t]     = mx;
    mp[128+t] = mn;
    part[(size_t)blockIdx.x*256 + t]       = sm;
    part[(size_t)blockIdx.x*256 + 128 + t] = sq;
  }
}

// ---------------------------------------------------------------------------
// K5b: reduce part[16384][256] -> st2 (interleaved {sum,sumsq} per channel).
// 256 blocks x 64 rows each; coalesced column sums; 65K atomics total.
// ---------------------------------------------------------------------------
__global__ __launch_bounds__(256) void reduce_kernel(const float* __restrict__ part,
                                                     float* __restrict__ st2){
  const int t=threadIdx.x;
  const int base = blockIdx.x*64;
  float acc=0.f;
  for (int r=0;r<64;++r) acc += part[(size_t)(base+r)*256 + t];
  if (t<128) atomicAdd(&st2[t*2], acc);
  else       atomicAdd(&st2[(t-128)*2+1], acc);
}

// ---------------------------------------------------------------------------
// K6: BN(stats2) on max (or min if scale<0) + ReLU -> new_points (f32).
// ---------------------------------------------------------------------------
__global__ __launch_bounds__(256) void final_kernel(const float* __restrict__ mm,
    const float* __restrict__ st, const float* __restrict__ g,
    const float* __restrict__ be, float* __restrict__ out){
  __shared__ float s_scale[128], s_shift[128];
  const int t=threadIdx.x;
  if (t<128){
    float mu=st[t*2]*(1.0f/NROWS);
    float var=st[t*2+1]*(1.0f/NROWS)-mu*mu;
    float inv=1.0f/sqrtf(var+1e-5f);
    s_scale[t]=inv*g[t]; s_shift[t]=be[t]-mu*inv*g[t];
  }
  __syncthreads();
  const int idx = blockIdx.x*256+t;       // bs*128 + ch
  const int ch = idx & 127, bs = idx >> 7;
  float sc=s_scale[ch];
  float v = (sc>=0.f)? mm[(size_t)bs*256+ch] : mm[(size_t)bs*256+128+ch];
  out[(size_t)NB*NPOINT*3 + idx] = fmaxf(fmaf(v,sc,s_shift[ch]),0.0f);
}

// ---------------------------------------------------------------------------
extern "C" void kernel_launch(void* const* d_in, const int* in_sizes, int n_in,
                              void* d_out, int out_size, void* d_ws, size_t ws_size,
                              hipStream_t stream) {
  const float* xyz    = (const float*)d_in[0];
  const float* points = (const float*)d_in[1];
  const float* w0 = (const float*)d_in[2];
  const float* b0 = (const float*)d_in[3];
  const float* g0 = (const float*)d_in[4];
  const float* be0= (const float*)d_in[5];
  const float* w1 = (const float*)d_in[6];
  const float* b1 = (const float*)d_in[7];
  const float* g1 = (const float*)d_in[8];
  const float* be1= (const float*)d_in[9];
  const float* w2 = (const float*)d_in[10];
  const float* b2 = (const float*)d_in[11];
  const float* g2 = (const float*)d_in[12];
  const float* be2= (const float*)d_in[13];
  float* out = (float*)d_out;             // f32 output per reference dtype
  char* ws = (char*)d_ws;

  // ws layout (100 MiB total):
  //   [0,        196608)    newxyz_f (16,1024,3) f32
  //   [196608,   2293760)   ballidx  (16,1024,32) i32
  //   [2293760,  2296832)   stats: 3 slots x 256 f32 {sum,sumsq interleaved}
  //   [4 MiB,    20 MiB)    mm: (16384, {max,min}, 128) f32
  //   [20 MiB,   84 MiB)    h: (524288, 64) bf16 — h1, then h2 in place
  //   [84 MiB,   100 MiB)   part: (16384, 256) f32 BN3 partial sums
  float* newxyz_f = (float*)(ws);
  int*   ballidx  = (int*)(ws + 196608);
  float* stats    = (float*)(ws + 2293760);
  float* mm       = (float*)(ws + 4194304);
  unsigned short* h = (unsigned short*)(ws + 20971520);
  float* part     = (float*)(ws + 88080384);

  hipMemsetAsync(stats, 0, 3072, stream);
  hipLaunchKernelGGL(fps_kernel,     dim3(NB),    dim3(512), 0, stream, xyz, newxyz_f, out);
  hipLaunchKernelGGL(ballq_kernel,   dim3(4096),  dim3(256), 0, stream, xyz, newxyz_f, ballidx);
  hipLaunchKernelGGL(layer1_kernel,  dim3(8192),  dim3(256), 0, stream,
                     xyz, points, ballidx, newxyz_f, w0, b0, h);
  hipLaunchKernelGGL(stats64_kernel, dim3(512),   dim3(256), 0, stream, h, stats + 0);
  hipLaunchKernelGGL(layer2_kernel,  dim3(4096),  dim3(256), 0, stream,
                     h, stats + 0, g0, be0, w1, b1);
  hipLaunchKernelGGL(stats64_kernel, dim3(512),   dim3(256), 0, stream, h, stats + 256);
  hipLaunchKernelGGL(layer3mm_kernel,dim3(16384), dim3(256), 0, stream,
                     h, stats + 256, g1, be1, w2, b2, mm, part);
  hipLaunchKernelGGL(reduce_kernel,  dim3(256),   dim3(256), 0, stream, part, stats + 512);
  hipLaunchKernelGGL(final_kernel,   dim3(8192),  dim3(256), 0, stream,
                     mm, stats + 512, g2, be2, out);
}

// Round 7
// 1488.513 us; speedup vs baseline: 4.0913x; 1.4456x over previous
//
#include <hip/hip_runtime.h>
#include <stdint.h>

// Problem constants
#define NB      16
#define NPTS    4096
#define CPTS    64
#define NPOINT  1024
#define NSAMPLE 32
#define NROWS   (NB*NPOINT*NSAMPLE)   // 524288 rows of (b,s,k)

// f32 -> bf16 (RNE) and bf16 -> f32 (intermediates only; in/out are f32)
__device__ __forceinline__ unsigned short f2bf(float f){
  uint32_t u = __float_as_uint(f);
  uint32_t r = u + 0x7fffu + ((u>>16)&1u);
  return (unsigned short)(r>>16);
}
__device__ __forceinline__ float bf2f(unsigned short u){ return __uint_as_float(((uint32_t)u)<<16); }
__device__ __forceinline__ float lo16(uint32_t d){ return __uint_as_float(d<<16); }
__device__ __forceinline__ float hi16(uint32_t d){ return __uint_as_float(d & 0xffff0000u); }
__device__ __forceinline__ uint32_t pack2(float a, float b){ return ((uint32_t)f2bf(b)<<16) | (uint32_t)f2bf(a); }

// ---------------------------------------------------------------------------
// K1: Farthest point sampling.  R6 post-mortem: old version was 1.42 us/iter,
// dominated by the 6-step two-value (float+int) shuffle chain (~2 dependent
// ds_bpermute round-trips per step) + 8-wave barrier + 16-read final reduce.
// Now: (dist,idx) packed into ONE u64 key = (f32bits(d)<<32)|~idx — dist>=0
// so f32 bits are order-isomorphic; ~idx gives np.argmax first-occurrence
// tie-break; u64 max == lexicographic (dist, -idx) max.  6 x shfl_xor(u64)
// (independent bpermute pair per step), 256 thr x 16 pts, cross-wave reduce
// = 4 packed LDS reads + 3 u64 max.  Selection arithmetic unchanged
// (__fsub_rn/__fmul_rn/__fadd_rn, fminf, strict >) => bit-identical indices.
// ---------------------------------------------------------------------------
__global__ __launch_bounds__(256) void fps_kernel(const float* __restrict__ xyz,
                                                  float* __restrict__ newxyz_f,
                                                  float* __restrict__ out){
  __shared__ float s_x[NPTS], s_y[NPTS], s_z[NPTS];
  __shared__ unsigned long long s_k[2][4];
  const int b = blockIdx.x, t = threadIdx.x;
  const float* Xb = xyz + (size_t)b*NPTS*3;
  float px[16], py[16], pz[16], dd[16];
  #pragma unroll
  for (int i=0;i<16;++i){
    int n = t*16+i;
    float x = Xb[n*3+0], y = Xb[n*3+1], z = Xb[n*3+2];
    px[i]=x; py[i]=y; pz[i]=z; dd[i]=1e10f;
    s_x[n]=x; s_y[n]=y; s_z[n]=z;
  }
  if (t==0){
    size_t o=(size_t)b*NPOINT*3;   // sample 0 is index 0 (scan emits prior carry)
    newxyz_f[o]=px[0]; newxyz_f[o+1]=py[0]; newxyz_f[o+2]=pz[0];
    out[o]=px[0]; out[o+1]=py[0]; out[o+2]=pz[0];
  }
  __syncthreads();
  float cx=s_x[0], cy=s_y[0], cz=s_z[0];
  const int lane = t&63, wid = t>>6;
  for (int s=1;s<NPOINT;++s){
    float bv=-1.0f; int bl=0;
    #pragma unroll
    for (int i=0;i<16;++i){
      float dx=__fsub_rn(px[i],cx), dy=__fsub_rn(py[i],cy), dz=__fsub_rn(pz[i],cz);
      float d=__fadd_rn(__fadd_rn(__fmul_rn(dx,dx),__fmul_rn(dy,dy)),__fmul_rn(dz,dz));
      float nd=fminf(dd[i],d); dd[i]=nd;
      if (nd>bv){ bv=nd; bl=i; }        // ascending i + strict > => lowest idx on tie
    }
    unsigned long long key =
      ((unsigned long long)__float_as_uint(bv)<<32) | (uint32_t)(~(t*16+bl));
    #pragma unroll
    for (int m=1;m<64;m<<=1){
      unsigned long long ok = __shfl_xor(key, m, 64);
      key = (ok>key)? ok : key;
    }
    const int buf = s&1;
    if (lane==0) s_k[buf][wid]=key;
    __syncthreads();
    unsigned long long k0=s_k[buf][0], k1=s_k[buf][1], k2=s_k[buf][2], k3=s_k[buf][3];
    unsigned long long ka=(k0>k1)?k0:k1, kb=(k2>k3)?k2:k3;
    unsigned long long kf=(ka>kb)?ka:kb;
    int fi = (int)(~(uint32_t)(kf & 0xffffffffu));
    cx=s_x[fi]; cy=s_y[fi]; cz=s_z[fi];
    if (t==0){
      size_t o=((size_t)b*NPOINT+s)*3;
      newxyz_f[o]=cx; newxyz_f[o+1]=cy; newxyz_f[o+2]=cz;
      out[o]=cx; out[o+1]=cy; out[o+2]=cz;
    }
    // no 2nd barrier: next iter writes the OTHER s_k buffer; reaching that
    // write requires passing this barrier, which all waves' reads precede.
  }
}

// ---------------------------------------------------------------------------
// K2: Ball query. One wave per center; batch xyz staged in LDS. First NSAMPLE
// in-radius indices in ascending j (== sort semantics) via ballot + prefix
// popcount; pad with first index.
// ---------------------------------------------------------------------------
__global__ __launch_bounds__(256) void ballq_kernel(const float* __restrict__ xyz,
                                                    const float* __restrict__ newxyz_f,
                                                    int* __restrict__ ballidx){
  __shared__ float s_x[NPTS], s_y[NPTS], s_z[NPTS];
  __shared__ int s_list[4][NSAMPLE];
  const int b  = blockIdx.x >> 8;     // 256 s-groups per batch
  const int sg = blockIdx.x & 255;
  const int t = threadIdx.x;
  const float* Xb = xyz + (size_t)b*NPTS*3;
  for (int n=t;n<NPTS;n+=256){
    s_x[n]=Xb[n*3+0]; s_y[n]=Xb[n*3+1]; s_z[n]=Xb[n*3+2];
  }
  __syncthreads();
  const int lane = t&63, wid = t>>6;
  const int s = sg*4 + wid;
  size_t co = ((size_t)b*NPOINT+s)*3;
  const float cx=newxyz_f[co], cy=newxyz_f[co+1], cz=newxyz_f[co+2];
  const float R2 = 0.04f;             // f32(0.2**2), NEP-50 weak-scalar promotion
  int count = 0;
  for (int j0=0; j0<NPTS && count<NSAMPLE; j0+=64){
    int j=j0+lane;
    float dx=__fsub_rn(cx,s_x[j]), dy=__fsub_rn(cy,s_y[j]), dz=__fsub_rn(cz,s_z[j]);
    float sq=__fadd_rn(__fadd_rn(__fmul_rn(dx,dx),__fmul_rn(dy,dy)),__fmul_rn(dz,dz));
    bool in = !(sq > R2);
    unsigned long long m = __ballot(in);
    int before = __popcll(m & ((1ull<<lane)-1ull));
    int pos = count + before;
    if (in && pos < NSAMPLE) s_list[wid][pos] = j;
    count += __popcll(m);
  }
  int c = count < NSAMPLE ? count : NSAMPLE;   // >=1: center is in its own ball
  int first = s_list[wid][0];
  if (lane >= c && lane < NSAMPLE) s_list[wid][lane] = first;
  if (lane < NSAMPLE) ballidx[((size_t)b*NPOINT+s)*NSAMPLE + lane] = s_list[wid][lane];
}

// ---------------------------------------------------------------------------
// K3: layer 1 — gather + concat + (67 -> 64) matmul + bias -> h (bf16).
// LDS-staged coalesced gather; 2 threads per row, acc[16] (no private arrays
// with dynamic indexing -> no scratch demotion).
// ---------------------------------------------------------------------------
#define L1_STRIDE 71
__global__ __launch_bounds__(256,3) void layer1_kernel(const float* __restrict__ xyz,
    const float* __restrict__ points, const int* __restrict__ ballidx,
    const float* __restrict__ newxyz_f, const float* __restrict__ w0,
    const float* __restrict__ b0, unsigned short* __restrict__ h){
  __shared__ float s_w[67*32];            // [c][o_local], c: 0..63=points, 64..66=xyz
  __shared__ float s_b[32];
  __shared__ float s_x[128*L1_STRIDE];    // 128 rows x 71 (67 used)
  __shared__ int   s_j[128];
  const int t = threadIdx.x;
  const int tile = blockIdx.x >> 1;       // 4096 tiles of 128 rows
  const int half = blockIdx.x & 1;        // output channels [half*32, half*32+32)
  const int tileBase = tile*128;
  for (int i=t;i<67*32;i+=256){
    int c=i>>5, oL=i&31;
    int srcc = (c<64) ? (c+3) : (c-64);
    s_w[i] = w0[(half*32+oL)*67 + srcc];
  }
  if (t<32) s_b[t]=b0[half*32+t];
  if (t<128) s_j[t]=ballidx[tileBase+t];
  __syncthreads();
  #pragma unroll
  for (int it=0; it<8; ++it){
    int r = it*16 + (t>>4);
    int row = tileBase + r;
    int bb = row >> 15;                   // 32768 rows per batch
    int j  = s_j[r];
    float4 pv = *(const float4*)(points + ((size_t)bb*NPTS + (size_t)j)*CPTS + (t&15)*4);
    float* xr = s_x + r*L1_STRIDE + (t&15)*4;
    xr[0]=pv.x; xr[1]=pv.y; xr[2]=pv.z; xr[3]=pv.w;
  }
  if (t<128){
    int row = tileBase + t;
    int bs  = row >> 5;
    int bb  = bs >> 10;
    int j   = s_j[t];
    const float* xr = xyz + ((size_t)bb*NPTS + (size_t)j)*3;
    const float* cp = newxyz_f + (size_t)bs*3;
    float* xd = s_x + t*L1_STRIDE + 64;
    xd[0]=(xr[0]-cp[0])/0.2f; xd[1]=(xr[1]-cp[1])/0.2f; xd[2]=(xr[2]-cp[2])/0.2f;
  }
  __syncthreads();
  const int r    = t & 127;
  const int osub = (t>>7)*16;
  const float* xp = s_x + r*L1_STRIDE;
  float acc[16];
  #pragma unroll
  for (int o=0;o<16;++o) acc[o]=0.0f;
  for (int c=0;c<67;++c){
    float xv = xp[c];
    const float4* wr=(const float4*)(s_w + c*32 + osub);
    #pragma unroll
    for (int q=0;q<4;++q){ float4 w=wr[q];
      acc[4*q+0]=fmaf(xv,w.x,acc[4*q+0]); acc[4*q+1]=fmaf(xv,w.y,acc[4*q+1]);
      acc[4*q+2]=fmaf(xv,w.z,acc[4*q+2]); acc[4*q+3]=fmaf(xv,w.w,acc[4*q+3]); }
  }
  uint4* od=(uint4*)(h + (size_t)(tileBase+r)*64 + half*32 + osub);
  #pragma unroll
  for (int q=0;q<2;++q){
    uint4 v;
    v.x=pack2(acc[8*q+0]+s_b[osub+8*q+0], acc[8*q+1]+s_b[osub+8*q+1]);
    v.y=pack2(acc[8*q+2]+s_b[osub+8*q+2], acc[8*q+3]+s_b[osub+8*q+3]);
    v.z=pack2(acc[8*q+4]+s_b[osub+8*q+4], acc[8*q+5]+s_b[osub+8*q+5]);
    v.w=pack2(acc[8*q+6]+s_b[osub+8*q+6], acc[8*q+7]+s_b[osub+8*q+7]);
    od[q]=v;
  }
}

// ---------------------------------------------------------------------------
// Stats over h (bf16, C=64): per-channel sum/sumsq, coalesced uint4 reads,
// LDS block-reduce, one atomicAdd pair per channel per block.
// ---------------------------------------------------------------------------
__global__ __launch_bounds__(256) void stats64_kernel(const unsigned short* __restrict__ h,
                                                      float* __restrict__ st){
  __shared__ float s_red[4][64][8], s_red2[4][64][8];
  const int t=threadIdx.x, lane=t&63, wid=t>>6;
  const int gw = blockIdx.x*4+wid;         // 512 blocks -> 0..2047 waves
  const int rsub = lane>>3;
  float sm[8], sq[8];
  #pragma unroll
  for (int j=0;j<8;++j){ sm[j]=0.f; sq[j]=0.f; }
  for (int it=0; it<32; ++it){
    size_t row = (size_t)gw*256 + it*8 + rsub;
    const uint4* p = (const uint4*)(h + row*64) + (lane&7);
    uint4 v = *p;
    uint32_t ds4[4]={v.x,v.y,v.z,v.w};
    #pragma unroll
    for (int dj=0;dj<4;++dj){
      float a=lo16(ds4[dj]), b2=hi16(ds4[dj]);
      sm[2*dj]+=a;   sq[2*dj]  =fmaf(a,a,sq[2*dj]);
      sm[2*dj+1]+=b2; sq[2*dj+1]=fmaf(b2,b2,sq[2*dj+1]);
    }
  }
  #pragma unroll
  for (int j=0;j<8;++j){ s_red[wid][lane][j]=sm[j]; s_red2[wid][lane][j]=sq[j]; }
  __syncthreads();
  if (t<64){
    float ts=0.f,tq=0.f;
    #pragma unroll
    for (int w=0;w<4;++w)
      #pragma unroll
      for (int m=0;m<8;++m){ int l=(t>>3)+8*m; ts+=s_red[w][l][t&7]; tq+=s_red2[w][l][t&7]; }
    atomicAdd(&st[t*2], ts); atomicAdd(&st[t*2+1], tq);
  }
}

// ---------------------------------------------------------------------------
// K4: layer 2 — (64 -> 64) matmul + bias, in place.  BN(stats0)+ReLU applied
// while staging 128 rows into an LDS tile (stride 65); 2 threads per row,
// acc[32] fully unrolled; no private arrays -> no scratch demotion.
// ---------------------------------------------------------------------------
__global__ __launch_bounds__(256,3) void layer2_kernel(unsigned short* __restrict__ h,
    const float* __restrict__ st, const float* __restrict__ g,
    const float* __restrict__ be, const float* __restrict__ w1,
    const float* __restrict__ b1){
  __shared__ float s_w[64*64];            // 16 KB  [c][o]
  __shared__ float s_x[128*65];           // 33.3 KB
  __shared__ float s_b[64], s_scale[64], s_shift[64];
  const int t=threadIdx.x;
  const int tileBase = blockIdx.x*128;    // 4096 blocks
  for (int i=t;i<64*64;i+=256){ int c=i>>6, o=i&63; s_w[i]=w1[o*64+c]; }
  if (t<64){
    s_b[t]=b1[t];
    float mu=st[t*2]*(1.0f/NROWS);
    float var=st[t*2+1]*(1.0f/NROWS)-mu*mu;
    float inv=1.0f/sqrtf(var+1e-5f);
    s_scale[t]=inv*g[t]; s_shift[t]=be[t]-mu*inv*g[t];
  }
  __syncthreads();
  #pragma unroll
  for (int it=0; it<4; ++it){
    int idx = it*256 + t;
    int r = idx>>3, seg = idx&7;
    uint4 v = *((const uint4*)(h + (size_t)(tileBase+r)*64) + seg);
    float* xd = s_x + r*65 + seg*8;
    uint32_t ds4[4]={v.x,v.y,v.z,v.w};
    #pragma unroll
    for (int dj=0;dj<4;++dj){
      int c = seg*8 + dj*2;
      xd[dj*2+0]=fmaxf(fmaf(lo16(ds4[dj]),s_scale[c],  s_shift[c]),  0.0f);
      xd[dj*2+1]=fmaxf(fmaf(hi16(ds4[dj]),s_scale[c+1],s_shift[c+1]),0.0f);
    }
  }
  __syncthreads();
  const int r    = t & 127;
  const int osub = (t>>7)*32;
  const float* xp = s_x + r*65;
  float acc[32];
  #pragma unroll
  for (int o=0;o<32;++o) acc[o]=0.0f;
  for (int c=0;c<64;++c){
    float xv = xp[c];
    const float4* wr=(const float4*)(s_w + c*64 + osub);
    #pragma unroll
    for (int q=0;q<8;++q){ float4 w=wr[q];
      acc[4*q+0]=fmaf(xv,w.x,acc[4*q+0]); acc[4*q+1]=fmaf(xv,w.y,acc[4*q+1]);
      acc[4*q+2]=fmaf(xv,w.z,acc[4*q+2]); acc[4*q+3]=fmaf(xv,w.w,acc[4*q+3]); }
  }
  uint4* od=(uint4*)(h + (size_t)(tileBase+r)*64 + osub);
  #pragma unroll
  for (int q=0;q<4;++q){
    uint4 v;
    v.x=pack2(acc[8*q+0]+s_b[osub+8*q+0], acc[8*q+1]+s_b[osub+8*q+1]);
    v.y=pack2(acc[8*q+2]+s_b[osub+8*q+2], acc[8*q+3]+s_b[osub+8*q+3]);
    v.z=pack2(acc[8*q+4]+s_b[osub+8*q+4], acc[8*q+5]+s_b[osub+8*q+5]);
    v.w=pack2(acc[8*q+6]+s_b[osub+8*q+6], acc[8*q+7]+s_b[osub+8*q+7]);
    od[q]=v;
  }
}

// ---------------------------------------------------------------------------
// K5: layer 3 fused — BN(stats1)+ReLU (at stage time), (64 -> 128) matmul +
// bias, per-s max/min over K=32 + BN3 partial sums.  One 32-row s-group per
// block (16384 blocks); x tile stride 65; out tile f32 stride 133; 8 threads
// per row x acc[16]; partial sums to part[] (atomic-free), reduced by K5b.
// ---------------------------------------------------------------------------
__global__ __launch_bounds__(256,3) void layer3mm_kernel(const unsigned short* __restrict__ h,
    const float* __restrict__ st, const float* __restrict__ g,
    const float* __restrict__ be, const float* __restrict__ w2,
    const float* __restrict__ b2, float* __restrict__ mm, float* __restrict__ part){
  __shared__ unsigned short s_w[64*128];  // 16 KB  s_w[c*128+o]=bf16(w2[o][c])
  __shared__ float s_x[32*65];            // 8.3 KB
  __shared__ float s_o[32*133];           // 17 KB
  __shared__ float s_scale[64], s_shift[64], s_b2[128];
  const int t=threadIdx.x;
  const int sgBase = blockIdx.x*32;       // row base of this s-group
  for (int i=t;i<64*128;i+=256){ int c=i>>7, o=i&127; s_w[i]=f2bf(w2[o*64+c]); }
  if (t<64){
    float mu=st[t*2]*(1.0f/NROWS);
    float var=st[t*2+1]*(1.0f/NROWS)-mu*mu;
    float inv=1.0f/sqrtf(var+1e-5f);
    s_scale[t]=inv*g[t]; s_shift[t]=be[t]-mu*inv*g[t];
  }
  if (t<128) s_b2[t]=b2[t];
  __syncthreads();
  {
    int r = t>>3, seg = t&7;
    uint4 v = *((const uint4*)(h + (size_t)(sgBase+r)*64) + seg);
    float* xd = s_x + r*65 + seg*8;
    uint32_t ds4[4]={v.x,v.y,v.z,v.w};
    #pragma unroll
    for (int dj=0;dj<4;++dj){
      int c = seg*8 + dj*2;
      xd[dj*2+0]=fmaxf(fmaf(lo16(ds4[dj]),s_scale[c],  s_shift[c]),  0.0f);
      xd[dj*2+1]=fmaxf(fmaf(hi16(ds4[dj]),s_scale[c+1],s_shift[c+1]),0.0f);
    }
  }
  __syncthreads();
  {
    const int r    = t & 31;
    const int osub = (t>>5)*16;
    const float* xp = s_x + r*65;
    float acc[16];
    #pragma unroll
    for (int o=0;o<16;++o) acc[o]=0.0f;
    for (int c=0;c<64;++c){
      float xv = xp[c];
      const uint4* wr=(const uint4*)(s_w + c*128 + osub);
      #pragma unroll
      for (int q=0;q<2;++q){
        uint4 wu=wr[q];
        acc[8*q+0]=fmaf(xv,lo16(wu.x),acc[8*q+0]); acc[8*q+1]=fmaf(xv,hi16(wu.x),acc[8*q+1]);
        acc[8*q+2]=fmaf(xv,lo16(wu.y),acc[8*q+2]); acc[8*q+3]=fmaf(xv,hi16(wu.y),acc[8*q+3]);
        acc[8*q+4]=fmaf(xv,lo16(wu.z),acc[8*q+4]); acc[8*q+5]=fmaf(xv,hi16(wu.z),acc[8*q+5]);
        acc[8*q+6]=fmaf(xv,lo16(wu.w),acc[8*q+6]); acc[8*q+7]=fmaf(xv,hi16(wu.w),acc[8*q+7]);
      }
    }
    float* op = s_o + r*133 + osub;
    #pragma unroll
    for (int o=0;o<16;++o) op[o] = acc[o] + s_b2[osub+o];
  }
  __syncthreads();
  if (t<128){
    float mx=-3e38f, mn=3e38f, sm=0.f, sq=0.f;
    #pragma unroll
    for (int r=0;r<32;++r){
      float v = s_o[r*133 + t];
      mx=fmaxf(mx,v); mn=fminf(mn,v); sm+=v; sq=fmaf(v,v,sq);
    }
    float* mp = mm + (size_t)blockIdx.x*256;
    mp[t]     = mx;
    mp[128+t] = mn;
    part[(size_t)blockIdx.x*256 + t]       = sm;
    part[(size_t)blockIdx.x*256 + 128 + t] = sq;
  }
}

// ---------------------------------------------------------------------------
// K5b: reduce part[16384][256] -> st2 (interleaved {sum,sumsq} per channel).
// ---------------------------------------------------------------------------
__global__ __launch_bounds__(256) void reduce_kernel(const float* __restrict__ part,
                                                     float* __restrict__ st2){
  const int t=threadIdx.x;
  const int base = blockIdx.x*64;
  float acc=0.f;
  for (int r=0;r<64;++r) acc += part[(size_t)(base+r)*256 + t];
  if (t<128) atomicAdd(&st2[t*2], acc);
  else       atomicAdd(&st2[(t-128)*2+1], acc);
}

// ---------------------------------------------------------------------------
// K6: BN(stats2) on max (or min if scale<0) + ReLU -> new_points (f32).
// ---------------------------------------------------------------------------
__global__ __launch_bounds__(256) void final_kernel(const float* __restrict__ mm,
    const float* __restrict__ st, const float* __restrict__ g,
    const float* __restrict__ be, float* __restrict__ out){
  __shared__ float s_scale[128], s_shift[128];
  const int t=threadIdx.x;
  if (t<128){
    float mu=st[t*2]*(1.0f/NROWS);
    float var=st[t*2+1]*(1.0f/NROWS)-mu*mu;
    float inv=1.0f/sqrtf(var+1e-5f);
    s_scale[t]=inv*g[t]; s_shift[t]=be[t]-mu*inv*g[t];
  }
  __syncthreads();
  const int idx = blockIdx.x*256+t;       // bs*128 + ch
  const int ch = idx & 127, bs = idx >> 7;
  float sc=s_scale[ch];
  float v = (sc>=0.f)? mm[(size_t)bs*256+ch] : mm[(size_t)bs*256+128+ch];
  out[(size_t)NB*NPOINT*3 + idx] = fmaxf(fmaf(v,sc,s_shift[ch]),0.0f);
}

// ---------------------------------------------------------------------------
extern "C" void kernel_launch(void* const* d_in, const int* in_sizes, int n_in,
                              void* d_out, int out_size, void* d_ws, size_t ws_size,
                              hipStream_t stream) {
  const float* xyz    = (const float*)d_in[0];
  const float* points = (const float*)d_in[1];
  const float* w0 = (const float*)d_in[2];
  const float* b0 = (const float*)d_in[3];
  const float* g0 = (const float*)d_in[4];
  const float* be0= (const float*)d_in[5];
  const float* w1 = (const float*)d_in[6];
  const float* b1 = (const float*)d_in[7];
  const float* g1 = (const float*)d_in[8];
  const float* be1= (const float*)d_in[9];
  const float* w2 = (const float*)d_in[10];
  const float* b2 = (const float*)d_in[11];
  const float* g2 = (const float*)d_in[12];
  const float* be2= (const float*)d_in[13];
  float* out = (float*)d_out;             // f32 output per reference dtype
  char* ws = (char*)d_ws;

  // ws layout (100 MiB total):
  //   [0,        196608)    newxyz_f (16,1024,3) f32
  //   [196608,   2293760)   ballidx  (16,1024,32) i32
  //   [2293760,  2296832)   stats: 3 slots x 256 f32 {sum,sumsq interleaved}
  //   [4 MiB,    20 MiB)    mm: (16384, {max,min}, 128) f32
  //   [20 MiB,   84 MiB)    h: (524288, 64) bf16 — h1, then h2 in place
  //   [84 MiB,   100 MiB)   part: (16384, 256) f32 BN3 partial sums
  float* newxyz_f = (float*)(ws);
  int*   ballidx  = (int*)(ws + 196608);
  float* stats    = (float*)(ws + 2293760);
  float* mm       = (float*)(ws + 4194304);
  unsigned short* h = (unsigned short*)(ws + 20971520);
  float* part     = (float*)(ws + 88080384);

  hipMemsetAsync(stats, 0, 3072, stream);
  hipLaunchKernelGGL(fps_kernel,     dim3(NB),    dim3(256), 0, stream, xyz, newxyz_f, out);
  hipLaunchKernelGGL(ballq_kernel,   dim3(4096),  dim3(256), 0, stream, xyz, newxyz_f, ballidx);
  hipLaunchKernelGGL(layer1_kernel,  dim3(8192),  dim3(256), 0, stream,
                     xyz, points, ballidx, newxyz_f, w0, b0, h);
  hipLaunchKernelGGL(stats64_kernel, dim3(512),   dim3(256), 0, stream, h, stats + 0);
  hipLaunchKernelGGL(layer2_kernel,  dim3(4096),  dim3(256), 0, stream,
                     h, stats + 0, g0, be0, w1, b1);
  hipLaunchKernelGGL(stats64_kernel, dim3(512),   dim3(256), 0, stream, h, stats + 256);
  hipLaunchKernelGGL(layer3mm_kernel,dim3(16384), dim3(256), 0, stream,
                     h, stats + 256, g1, be1, w2, b2, mm, part);
  hipLaunchKernelGGL(reduce_kernel,  dim3(256),   dim3(256), 0, stream, part, stats + 512);
  hipLaunchKernelGGL(final_kernel,   dim3(8192),  dim3(256), 0, stream,
                     mm, stats + 512, g2, be2, out);
}

// Round 8
// 1308.110 us; speedup vs baseline: 4.6555x; 1.1379x over previous
//
#include <hip/hip_runtime.h>
#include <stdint.h>

// Problem constants
#define NB      16
#define NPTS    4096
#define CPTS    64
#define NPOINT  1024
#define NSAMPLE 32
#define NROWS   (NB*NPOINT*NSAMPLE)   // 524288 rows of (b,s,k)

// f32 -> bf16 (RNE) and bf16 -> f32 (intermediates only; in/out are f32)
__device__ __forceinline__ unsigned short f2bf(float f){
  uint32_t u = __float_as_uint(f);
  uint32_t r = u + 0x7fffu + ((u>>16)&1u);
  return (unsigned short)(r>>16);
}
__device__ __forceinline__ float bf2f(unsigned short u){ return __uint_as_float(((uint32_t)u)<<16); }
__device__ __forceinline__ float lo16(uint32_t d){ return __uint_as_float(d<<16); }
__device__ __forceinline__ float hi16(uint32_t d){ return __uint_as_float(d & 0xffff0000u); }
__device__ __forceinline__ uint32_t pack2(float a, float b){ return ((uint32_t)f2bf(b)<<16) | (uint32_t)f2bf(a); }

// u64 cross-lane max via DPP (VALU, ~2-4cyc/step) instead of ds_bpermute
// (~120cyc/step).  Sequence: row_shr 1/2/4/8 -> lane15/31/47/63 hold row max;
// row_bcast15 + row_bcast31 fold rows -> lane 63 holds wave max.  bound_ctrl
// gives 0 for invalid lanes; 0 is a safe identity (all keys > 0).
#define DPP_PAIR(k, CTRL) \
  ( ((unsigned long long)(uint32_t)__builtin_amdgcn_update_dpp(0, (int)(uint32_t)((k)>>32), CTRL, 0xF, 0xF, true) << 32) \
    | (uint32_t)__builtin_amdgcn_update_dpp(0, (int)(uint32_t)(k), CTRL, 0xF, 0xF, true) )

// ---------------------------------------------------------------------------
// K1: Farthest point sampling.  R7 post-mortem: 6-step shfl_xor(u64) butterfly
// = 6 dependent LDS-pipe round-trips (~700cyc) dominated the 1830cyc/iter.
// Now the wave reduction is 6 DPP compare-select steps (~100cyc total) +
// readlane(63).  Key = (f32bits(d)<<32)|~idx — dist>=0 so f32 bits are
// order-isomorphic; ~idx gives np.argmax first-occurrence tie-break.
// Selection arithmetic unchanged (__fsub_rn/__fmul_rn/__fadd_rn, fminf,
// strict >) => bit-identical indices vs R3-R7 passing versions.
// ---------------------------------------------------------------------------
__global__ __launch_bounds__(256) void fps_kernel(const float* __restrict__ xyz,
                                                  float* __restrict__ newxyz_f,
                                                  float* __restrict__ out){
  __shared__ float s_x[NPTS], s_y[NPTS], s_z[NPTS];
  __shared__ unsigned long long s_k[2][4];
  const int b = blockIdx.x, t = threadIdx.x;
  const float* Xb = xyz + (size_t)b*NPTS*3;
  float px[16], py[16], pz[16], dd[16];
  #pragma unroll
  for (int i=0;i<16;++i){
    int n = t*16+i;
    float x = Xb[n*3+0], y = Xb[n*3+1], z = Xb[n*3+2];
    px[i]=x; py[i]=y; pz[i]=z; dd[i]=1e10f;
    s_x[n]=x; s_y[n]=y; s_z[n]=z;
  }
  if (t==0){
    size_t o=(size_t)b*NPOINT*3;   // sample 0 is index 0 (scan emits prior carry)
    newxyz_f[o]=px[0]; newxyz_f[o+1]=py[0]; newxyz_f[o+2]=pz[0];
    out[o]=px[0]; out[o+1]=py[0]; out[o+2]=pz[0];
  }
  __syncthreads();
  float cx=s_x[0], cy=s_y[0], cz=s_z[0];
  const int lane = t&63, wid = t>>6;
  for (int s=1;s<NPOINT;++s){
    float bv=-1.0f; int bl=0;
    #pragma unroll
    for (int i=0;i<16;++i){
      float dx=__fsub_rn(px[i],cx), dy=__fsub_rn(py[i],cy), dz=__fsub_rn(pz[i],cz);
      float d=__fadd_rn(__fadd_rn(__fmul_rn(dx,dx),__fmul_rn(dy,dy)),__fmul_rn(dz,dz));
      float nd=fminf(dd[i],d); dd[i]=nd;
      if (nd>bv){ bv=nd; bl=i; }        // ascending i + strict > => lowest idx on tie
    }
    unsigned long long key =
      ((unsigned long long)__float_as_uint(bv)<<32) | (uint32_t)(~(t*16+bl));
    unsigned long long o;
    o = DPP_PAIR(key,0x111); key = (o>key)?o:key;   // row_shr:1
    o = DPP_PAIR(key,0x112); key = (o>key)?o:key;   // row_shr:2
    o = DPP_PAIR(key,0x114); key = (o>key)?o:key;   // row_shr:4
    o = DPP_PAIR(key,0x118); key = (o>key)?o:key;   // row_shr:8
    o = DPP_PAIR(key,0x142); key = (o>key)?o:key;   // row_bcast:15
    o = DPP_PAIR(key,0x143); key = (o>key)?o:key;   // row_bcast:31
    uint32_t klo = (uint32_t)__builtin_amdgcn_readlane((int)(uint32_t)key, 63);
    uint32_t khi = (uint32_t)__builtin_amdgcn_readlane((int)(uint32_t)(key>>32), 63);
    unsigned long long wkey = ((unsigned long long)khi<<32)|klo;
    const int buf = s&1;
    if (lane==0) s_k[buf][wid]=wkey;
    __syncthreads();
    unsigned long long k0=s_k[buf][0], k1=s_k[buf][1], k2=s_k[buf][2], k3=s_k[buf][3];
    unsigned long long ka=(k0>k1)?k0:k1, kb=(k2>k3)?k2:k3;
    unsigned long long kf=(ka>kb)?ka:kb;
    int fi = (int)(~(uint32_t)(kf & 0xffffffffu));
    cx=s_x[fi]; cy=s_y[fi]; cz=s_z[fi];
    if (t==0){
      size_t o2=((size_t)b*NPOINT+s)*3;
      newxyz_f[o2]=cx; newxyz_f[o2+1]=cy; newxyz_f[o2+2]=cz;
      out[o2]=cx; out[o2+1]=cy; out[o2+2]=cz;
    }
    // no 2nd barrier: next iter writes the OTHER s_k buffer; reaching that
    // write requires passing this barrier, which all waves' reads precede.
  }
}

// ---------------------------------------------------------------------------
// K2: Ball query. One wave per center; batch xyz staged in LDS. First NSAMPLE
// in-radius indices in ascending j (== sort semantics) via ballot + prefix
// popcount; pad with first index.
// ---------------------------------------------------------------------------
__global__ __launch_bounds__(256) void ballq_kernel(const float* __restrict__ xyz,
                                                    const float* __restrict__ newxyz_f,
                                                    int* __restrict__ ballidx){
  __shared__ float s_x[NPTS], s_y[NPTS], s_z[NPTS];
  __shared__ int s_list[4][NSAMPLE];
  const int b  = blockIdx.x >> 8;     // 256 s-groups per batch
  const int sg = blockIdx.x & 255;
  const int t = threadIdx.x;
  const float* Xb = xyz + (size_t)b*NPTS*3;
  for (int n=t;n<NPTS;n+=256){
    s_x[n]=Xb[n*3+0]; s_y[n]=Xb[n*3+1]; s_z[n]=Xb[n*3+2];
  }
  __syncthreads();
  const int lane = t&63, wid = t>>6;
  const int s = sg*4 + wid;
  size_t co = ((size_t)b*NPOINT+s)*3;
  const float cx=newxyz_f[co], cy=newxyz_f[co+1], cz=newxyz_f[co+2];
  const float R2 = 0.04f;             // f32(0.2**2), NEP-50 weak-scalar promotion
  int count = 0;
  for (int j0=0; j0<NPTS && count<NSAMPLE; j0+=64){
    int j=j0+lane;
    float dx=__fsub_rn(cx,s_x[j]), dy=__fsub_rn(cy,s_y[j]), dz=__fsub_rn(cz,s_z[j]);
    float sq=__fadd_rn(__fadd_rn(__fmul_rn(dx,dx),__fmul_rn(dy,dy)),__fmul_rn(dz,dz));
    bool in = !(sq > R2);
    unsigned long long m = __ballot(in);
    int before = __popcll(m & ((1ull<<lane)-1ull));
    int pos = count + before;
    if (in && pos < NSAMPLE) s_list[wid][pos] = j;
    count += __popcll(m);
  }
  int c = count < NSAMPLE ? count : NSAMPLE;   // >=1: center is in its own ball
  int first = s_list[wid][0];
  if (lane >= c && lane < NSAMPLE) s_list[wid][lane] = first;
  if (lane < NSAMPLE) ballidx[((size_t)b*NPOINT+s)*NSAMPLE + lane] = s_list[wid][lane];
}

// ---------------------------------------------------------------------------
// K3: layer 1 — gather + concat + (67 -> 64) matmul + bias -> h (bf16).
// LDS-staged coalesced gather; 2 threads per row, acc[16] (no private arrays
// with dynamic indexing -> no scratch demotion).
// ---------------------------------------------------------------------------
#define L1_STRIDE 71
__global__ __launch_bounds__(256,3) void layer1_kernel(const float* __restrict__ xyz,
    const float* __restrict__ points, const int* __restrict__ ballidx,
    const float* __restrict__ newxyz_f, const float* __restrict__ w0,
    const float* __restrict__ b0, unsigned short* __restrict__ h){
  __shared__ float s_w[67*32];            // [c][o_local], c: 0..63=points, 64..66=xyz
  __shared__ float s_b[32];
  __shared__ float s_x[128*L1_STRIDE];    // 128 rows x 71 (67 used)
  __shared__ int   s_j[128];
  const int t = threadIdx.x;
  const int tile = blockIdx.x >> 1;       // 4096 tiles of 128 rows
  const int half = blockIdx.x & 1;        // output channels [half*32, half*32+32)
  const int tileBase = tile*128;
  for (int i=t;i<67*32;i+=256){
    int c=i>>5, oL=i&31;
    int srcc = (c<64) ? (c+3) : (c-64);
    s_w[i] = w0[(half*32+oL)*67 + srcc];
  }
  if (t<32) s_b[t]=b0[half*32+t];
  if (t<128) s_j[t]=ballidx[tileBase+t];
  __syncthreads();
  #pragma unroll
  for (int it=0; it<8; ++it){
    int r = it*16 + (t>>4);
    int row = tileBase + r;
    int bb = row >> 15;                   // 32768 rows per batch
    int j  = s_j[r];
    float4 pv = *(const float4*)(points + ((size_t)bb*NPTS + (size_t)j)*CPTS + (t&15)*4);
    float* xr = s_x + r*L1_STRIDE + (t&15)*4;
    xr[0]=pv.x; xr[1]=pv.y; xr[2]=pv.z; xr[3]=pv.w;
  }
  if (t<128){
    int row = tileBase + t;
    int bs  = row >> 5;
    int bb  = bs >> 10;
    int j   = s_j[t];
    const float* xr = xyz + ((size_t)bb*NPTS + (size_t)j)*3;
    const float* cp = newxyz_f + (size_t)bs*3;
    float* xd = s_x + t*L1_STRIDE + 64;
    xd[0]=(xr[0]-cp[0])/0.2f; xd[1]=(xr[1]-cp[1])/0.2f; xd[2]=(xr[2]-cp[2])/0.2f;
  }
  __syncthreads();
  const int r    = t & 127;
  const int osub = (t>>7)*16;
  const float* xp = s_x + r*L1_STRIDE;
  float acc[16];
  #pragma unroll
  for (int o=0;o<16;++o) acc[o]=0.0f;
  for (int c=0;c<67;++c){
    float xv = xp[c];
    const float4* wr=(const float4*)(s_w + c*32 + osub);
    #pragma unroll
    for (int q=0;q<4;++q){ float4 w=wr[q];
      acc[4*q+0]=fmaf(xv,w.x,acc[4*q+0]); acc[4*q+1]=fmaf(xv,w.y,acc[4*q+1]);
      acc[4*q+2]=fmaf(xv,w.z,acc[4*q+2]); acc[4*q+3]=fmaf(xv,w.w,acc[4*q+3]); }
  }
  uint4* od=(uint4*)(h + (size_t)(tileBase+r)*64 + half*32 + osub);
  #pragma unroll
  for (int q=0;q<2;++q){
    uint4 v;
    v.x=pack2(acc[8*q+0]+s_b[osub+8*q+0], acc[8*q+1]+s_b[osub+8*q+1]);
    v.y=pack2(acc[8*q+2]+s_b[osub+8*q+2], acc[8*q+3]+s_b[osub+8*q+3]);
    v.z=pack2(acc[8*q+4]+s_b[osub+8*q+4], acc[8*q+5]+s_b[osub+8*q+5]);
    v.w=pack2(acc[8*q+6]+s_b[osub+8*q+6], acc[8*q+7]+s_b[osub+8*q+7]);
    od[q]=v;
  }
}

// ---------------------------------------------------------------------------
// Stats over h (bf16, C=64): per-channel sum/sumsq, coalesced uint4 reads,
// LDS block-reduce, one atomicAdd pair per channel per block.
// ---------------------------------------------------------------------------
__global__ __launch_bounds__(256) void stats64_kernel(const unsigned short* __restrict__ h,
                                                      float* __restrict__ st){
  __shared__ float s_red[4][64][8], s_red2[4][64][8];
  const int t=threadIdx.x, lane=t&63, wid=t>>6;
  const int gw = blockIdx.x*4+wid;         // 512 blocks -> 0..2047 waves
  const int rsub = lane>>3;
  float sm[8], sq[8];
  #pragma unroll
  for (int j=0;j<8;++j){ sm[j]=0.f; sq[j]=0.f; }
  for (int it=0; it<32; ++it){
    size_t row = (size_t)gw*256 + it*8 + rsub;
    const uint4* p = (const uint4*)(h + row*64) + (lane&7);
    uint4 v = *p;
    uint32_t ds4[4]={v.x,v.y,v.z,v.w};
    #pragma unroll
    for (int dj=0;dj<4;++dj){
      float a=lo16(ds4[dj]), b2=hi16(ds4[dj]);
      sm[2*dj]+=a;   sq[2*dj]  =fmaf(a,a,sq[2*dj]);
      sm[2*dj+1]+=b2; sq[2*dj+1]=fmaf(b2,b2,sq[2*dj+1]);
    }
  }
  #pragma unroll
  for (int j=0;j<8;++j){ s_red[wid][lane][j]=sm[j]; s_red2[wid][lane][j]=sq[j]; }
  __syncthreads();
  if (t<64){
    float ts=0.f,tq=0.f;
    #pragma unroll
    for (int w=0;w<4;++w)
      #pragma unroll
      for (int m=0;m<8;++m){ int l=(t>>3)+8*m; ts+=s_red[w][l][t&7]; tq+=s_red2[w][l][t&7]; }
    atomicAdd(&st[t*2], ts); atomicAdd(&st[t*2+1], tq);
  }
}

// ---------------------------------------------------------------------------
// K4: layer 2 — (64 -> 64) matmul + bias, in place.  BN(stats0)+ReLU applied
// while staging 128 rows into an LDS tile (stride 65); 2 threads per row,
// acc[32] fully unrolled; no private arrays -> no scratch demotion.
// ---------------------------------------------------------------------------
__global__ __launch_bounds__(256,3) void layer2_kernel(unsigned short* __restrict__ h,
    const float* __restrict__ st, const float* __restrict__ g,
    const float* __restrict__ be, const float* __restrict__ w1,
    const float* __restrict__ b1){
  __shared__ float s_w[64*64];            // 16 KB  [c][o]
  __shared__ float s_x[128*65];           // 33.3 KB
  __shared__ float s_b[64], s_scale[64], s_shift[64];
  const int t=threadIdx.x;
  const int tileBase = blockIdx.x*128;    // 4096 blocks
  for (int i=t;i<64*64;i+=256){ int c=i>>6, o=i&63; s_w[i]=w1[o*64+c]; }
  if (t<64){
    s_b[t]=b1[t];
    float mu=st[t*2]*(1.0f/NROWS);
    float var=st[t*2+1]*(1.0f/NROWS)-mu*mu;
    float inv=1.0f/sqrtf(var+1e-5f);
    s_scale[t]=inv*g[t]; s_shift[t]=be[t]-mu*inv*g[t];
  }
  __syncthreads();
  #pragma unroll
  for (int it=0; it<4; ++it){
    int idx = it*256 + t;
    int r = idx>>3, seg = idx&7;
    uint4 v = *((const uint4*)(h + (size_t)(tileBase+r)*64) + seg);
    float* xd = s_x + r*65 + seg*8;
    uint32_t ds4[4]={v.x,v.y,v.z,v.w};
    #pragma unroll
    for (int dj=0;dj<4;++dj){
      int c = seg*8 + dj*2;
      xd[dj*2+0]=fmaxf(fmaf(lo16(ds4[dj]),s_scale[c],  s_shift[c]),  0.0f);
      xd[dj*2+1]=fmaxf(fmaf(hi16(ds4[dj]),s_scale[c+1],s_shift[c+1]),0.0f);
    }
  }
  __syncthreads();
  const int r    = t & 127;
  const int osub = (t>>7)*32;
  const float* xp = s_x + r*65;
  float acc[32];
  #pragma unroll
  for (int o=0;o<32;++o) acc[o]=0.0f;
  for (int c=0;c<64;++c){
    float xv = xp[c];
    const float4* wr=(const float4*)(s_w + c*64 + osub);
    #pragma unroll
    for (int q=0;q<8;++q){ float4 w=wr[q];
      acc[4*q+0]=fmaf(xv,w.x,acc[4*q+0]); acc[4*q+1]=fmaf(xv,w.y,acc[4*q+1]);
      acc[4*q+2]=fmaf(xv,w.z,acc[4*q+2]); acc[4*q+3]=fmaf(xv,w.w,acc[4*q+3]); }
  }
  uint4* od=(uint4*)(h + (size_t)(tileBase+r)*64 + osub);
  #pragma unroll
  for (int q=0;q<4;++q){
    uint4 v;
    v.x=pack2(acc[8*q+0]+s_b[osub+8*q+0], acc[8*q+1]+s_b[osub+8*q+1]);
    v.y=pack2(acc[8*q+2]+s_b[osub+8*q+2], acc[8*q+3]+s_b[osub+8*q+3]);
    v.z=pack2(acc[8*q+4]+s_b[osub+8*q+4], acc[8*q+5]+s_b[osub+8*q+5]);
    v.w=pack2(acc[8*q+6]+s_b[osub+8*q+6], acc[8*q+7]+s_b[osub+8*q+7]);
    od[q]=v;
  }
}

// ---------------------------------------------------------------------------
// K5: layer 3 fused — BN(stats1)+ReLU (at stage time), (64 -> 128) matmul +
// bias, per-s max/min over K=32 + BN3 partial sums.  One 32-row s-group per
// block (16384 blocks); x tile stride 65; out tile f32 stride 133; 8 threads
// per row x acc[16]; partial sums to part[] (atomic-free), reduced by K5b.
// ---------------------------------------------------------------------------
__global__ __launch_bounds__(256,3) void layer3mm_kernel(const unsigned short* __restrict__ h,
    const float* __restrict__ st, const float* __restrict__ g,
    const float* __restrict__ be, const float* __restrict__ w2,
    const float* __restrict__ b2, float* __restrict__ mm, float* __restrict__ part){
  __shared__ unsigned short s_w[64*128];  // 16 KB  s_w[c*128+o]=bf16(w2[o][c])
  __shared__ float s_x[32*65];            // 8.3 KB
  __shared__ float s_o[32*133];           // 17 KB
  __shared__ float s_scale[64], s_shift[64], s_b2[128];
  const int t=threadIdx.x;
  const int sgBase = blockIdx.x*32;       // row base of this s-group
  for (int i=t;i<64*128;i+=256){ int c=i>>7, o=i&127; s_w[i]=f2bf(w2[o*64+c]); }
  if (t<64){
    float mu=st[t*2]*(1.0f/NROWS);
    float var=st[t*2+1]*(1.0f/NROWS)-mu*mu;
    float inv=1.0f/sqrtf(var+1e-5f);
    s_scale[t]=inv*g[t]; s_shift[t]=be[t]-mu*inv*g[t];
  }
  if (t<128) s_b2[t]=b2[t];
  __syncthreads();
  {
    int r = t>>3, seg = t&7;
    uint4 v = *((const uint4*)(h + (size_t)(sgBase+r)*64) + seg);
    float* xd = s_x + r*65 + seg*8;
    uint32_t ds4[4]={v.x,v.y,v.z,v.w};
    #pragma unroll
    for (int dj=0;dj<4;++dj){
      int c = seg*8 + dj*2;
      xd[dj*2+0]=fmaxf(fmaf(lo16(ds4[dj]),s_scale[c],  s_shift[c]),  0.0f);
      xd[dj*2+1]=fmaxf(fmaf(hi16(ds4[dj]),s_scale[c+1],s_shift[c+1]),0.0f);
    }
  }
  __syncthreads();
  {
    const int r    = t & 31;
    const int osub = (t>>5)*16;
    const float* xp = s_x + r*65;
    float acc[16];
    #pragma unroll
    for (int o=0;o<16;++o) acc[o]=0.0f;
    for (int c=0;c<64;++c){
      float xv = xp[c];
      const uint4* wr=(const uint4*)(s_w + c*128 + osub);
      #pragma unroll
      for (int q=0;q<2;++q){
        uint4 wu=wr[q];
        acc[8*q+0]=fmaf(xv,lo16(wu.x),acc[8*q+0]); acc[8*q+1]=fmaf(xv,hi16(wu.x),acc[8*q+1]);
        acc[8*q+2]=fmaf(xv,lo16(wu.y),acc[8*q+2]); acc[8*q+3]=fmaf(xv,hi16(wu.y),acc[8*q+3]);
        acc[8*q+4]=fmaf(xv,lo16(wu.z),acc[8*q+4]); acc[8*q+5]=fmaf(xv,hi16(wu.z),acc[8*q+5]);
        acc[8*q+6]=fmaf(xv,lo16(wu.w),acc[8*q+6]); acc[8*q+7]=fmaf(xv,hi16(wu.w),acc[8*q+7]);
      }
    }
    float* op = s_o + r*133 + osub;
    #pragma unroll
    for (int o=0;o<16;++o) op[o] = acc[o] + s_b2[osub+o];
  }
  __syncthreads();
  if (t<128){
    float mx=-3e38f, mn=3e38f, sm=0.f, sq=0.f;
    #pragma unroll
    for (int r=0;r<32;++r){
      float v = s_o[r*133 + t];
      mx=fmaxf(mx,v); mn=fminf(mn,v); sm+=v; sq=fmaf(v,v,sq);
    }
    float* mp = mm + (size_t)blockIdx.x*256;
    mp[t]     = mx;
    mp[128+t] = mn;
    part[(size_t)blockIdx.x*256 + t]       = sm;
    part[(size_t)blockIdx.x*256 + 128 + t] = sq;
  }
}

// ---------------------------------------------------------------------------
// K5b: reduce part[16384][256] -> st2 (interleaved {sum,sumsq} per channel).
// ---------------------------------------------------------------------------
__global__ __launch_bounds__(256) void reduce_kernel(const float* __restrict__ part,
                                                     float* __restrict__ st2){
  const int t=threadIdx.x;
  const int base = blockIdx.x*64;
  float acc=0.f;
  for (int r=0;r<64;++r) acc += part[(size_t)(base+r)*256 + t];
  if (t<128) atomicAdd(&st2[t*2], acc);
  else       atomicAdd(&st2[(t-128)*2+1], acc);
}

// ---------------------------------------------------------------------------
// K6: BN(stats2) on max (or min if scale<0) + ReLU -> new_points (f32).
// ---------------------------------------------------------------------------
__global__ __launch_bounds__(256) void final_kernel(const float* __restrict__ mm,
    const float* __restrict__ st, const float* __restrict__ g,
    const float* __restrict__ be, float* __restrict__ out){
  __shared__ float s_scale[128], s_shift[128];
  const int t=threadIdx.x;
  if (t<128){
    float mu=st[t*2]*(1.0f/NROWS);
    float var=st[t*2+1]*(1.0f/NROWS)-mu*mu;
    float inv=1.0f/sqrtf(var+1e-5f);
    s_scale[t]=inv*g[t]; s_shift[t]=be[t]-mu*inv*g[t];
  }
  __syncthreads();
  const int idx = blockIdx.x*256+t;       // bs*128 + ch
  const int ch = idx & 127, bs = idx >> 7;
  float sc=s_scale[ch];
  float v = (sc>=0.f)? mm[(size_t)bs*256+ch] : mm[(size_t)bs*256+128+ch];
  out[(size_t)NB*NPOINT*3 + idx] = fmaxf(fmaf(v,sc,s_shift[ch]),0.0f);
}

// ---------------------------------------------------------------------------
extern "C" void kernel_launch(void* const* d_in, const int* in_sizes, int n_in,
                              void* d_out, int out_size, void* d_ws, size_t ws_size,
                              hipStream_t stream) {
  const float* xyz    = (const float*)d_in[0];
  const float* points = (const float*)d_in[1];
  const float* w0 = (const float*)d_in[2];
  const float* b0 = (const float*)d_in[3];
  const float* g0 = (const float*)d_in[4];
  const float* be0= (const float*)d_in[5];
  const float* w1 = (const float*)d_in[6];
  const float* b1 = (const float*)d_in[7];
  const float* g1 = (const float*)d_in[8];
  const float* be1= (const float*)d_in[9];
  const float* w2 = (const float*)d_in[10];
  const float* b2 = (const float*)d_in[11];
  const float* g2 = (const float*)d_in[12];
  const float* be2= (const float*)d_in[13];
  float* out = (float*)d_out;             // f32 output per reference dtype
  char* ws = (char*)d_ws;

  // ws layout (100 MiB total):
  //   [0,        196608)    newxyz_f (16,1024,3) f32
  //   [196608,   2293760)   ballidx  (16,1024,32) i32
  //   [2293760,  2296832)   stats: 3 slots x 256 f32 {sum,sumsq interleaved}
  //   [4 MiB,    20 MiB)    mm: (16384, {max,min}, 128) f32
  //   [20 MiB,   84 MiB)    h: (524288, 64) bf16 — h1, then h2 in place
  //   [84 MiB,   100 MiB)   part: (16384, 256) f32 BN3 partial sums
  float* newxyz_f = (float*)(ws);
  int*   ballidx  = (int*)(ws + 196608);
  float* stats    = (float*)(ws + 2293760);
  float* mm       = (float*)(ws + 4194304);
  unsigned short* h = (unsigned short*)(ws + 20971520);
  float* part     = (float*)(ws + 88080384);

  hipMemsetAsync(stats, 0, 3072, stream);
  hipLaunchKernelGGL(fps_kernel,     dim3(NB),    dim3(256), 0, stream, xyz, newxyz_f, out);
  hipLaunchKernelGGL(ballq_kernel,   dim3(4096),  dim3(256), 0, stream, xyz, newxyz_f, ballidx);
  hipLaunchKernelGGL(layer1_kernel,  dim3(8192),  dim3(256), 0, stream,
                     xyz, points, ballidx, newxyz_f, w0, b0, h);
  hipLaunchKernelGGL(stats64_kernel, dim3(512),   dim3(256), 0, stream, h, stats + 0);
  hipLaunchKernelGGL(layer2_kernel,  dim3(4096),  dim3(256), 0, stream,
                     h, stats + 0, g0, be0, w1, b1);
  hipLaunchKernelGGL(stats64_kernel, dim3(512),   dim3(256), 0, stream, h, stats + 256);
  hipLaunchKernelGGL(layer3mm_kernel,dim3(16384), dim3(256), 0, stream,
                     h, stats + 256, g1, be1, w2, b2, mm, part);
  hipLaunchKernelGGL(reduce_kernel,  dim3(256),   dim3(256), 0, stream, part, stats + 512);
  hipLaunchKernelGGL(final_kernel,   dim3(8192),  dim3(256), 0, stream,
                     mm, stats + 512, g2, be2, out);
}